// Round 14
// baseline (824.829 us; speedup 1.0000x reference)
//
#include <hip/hip_runtime.h>
#include <hip/hip_bf16.h>

#define TT 512
#define MCELLS 16384            // B*N = 256*64
#define LOG2E 1.44269504088896340736f
#define LN2   0.69314718055994530942f

typedef __attribute__((ext_vector_type(8))) short bf16x8;
typedef __attribute__((ext_vector_type(4))) float f32x4;

__device__ __forceinline__ short f2bf(float f) {
    __hip_bfloat16 h = __float2bfloat16(f);
    return __builtin_bit_cast(short, h);
}

// Validated tanh LUT (R10): DIRECT array indexing only. (sigma-via-LUT failed
// 3x at ~3e-2 -- R8/R9/R11 anomaly, abandoned. sigma stays on exp2.)
// tanh table: domain [-8,8], step 1/128, 2048 intervals + guard.
#define LUT_TANH(xv, dst) {                                            \
    const float _c = __builtin_amdgcn_fmed3f((xv), -8.0f, 7.9921875f); \
    const float _u = fmaf(_c, 128.0f, 1024.0f);                        \
    const int   _i = (int)_u;                                          \
    const float _f = _u - (float)_i;                                   \
    (dst) = fmaf(_f, tanD[_i], tanY[_i]); }

// Persistent LSTM, 8 waves/SIMD, register diet v2 (R13 still spilled).
// grid = 1024 blocks x 512 threads (8 waves) = 4 blocks/CU = 32 waves/CU.
// Block owns 16 cells (cell = blockIdx*16 + (lane&15)). Wave w owns hdims
// [8w, 8w+8) via TWO gate-interleaved 16x16 MFMA tiles T = 2w, 2w+1:
//   tile T row rho = (gate = rho&3, hdim = 4T + (rho>>2))
// giving acc[t2][r] = gate r of (cell=lane&15, hdim=4T+hi): complete
// (i,f,g,o) quads, 2 elems/lane. Bias/x*W_ih via f32 init from LDS wib.
// Diet v2: g-dot MFMA is CONDITIONAL (wave w needs accg only at steps
// (t+1)&7==wv, 1-in-8) with its A-fragments reloaded from LDS (wgF) inside
// the branch -- AWg is no longer persistent (-8 regs) and accg's transient
// window no longer overlaps the acc/activation peak. Single fused rcp per
// elem (R = rcp(A1*A2*Od)): trans/elem 5 -> 4.
__global__ __launch_bounds__(512, 8)
void lstm_net_kernel(const float* __restrict__ input,
                     const float* __restrict__ w1,
                     const float* __restrict__ b1,
                     const float* __restrict__ w2,
                     const float* __restrict__ b2,
                     const float* __restrict__ W_ih,
                     const float* __restrict__ W_hh,
                     const float* __restrict__ b_ih,
                     const float* __restrict__ b_hh,
                     const float* __restrict__ wg,
                     const float* __restrict__ bg,
                     float* __restrict__ out)
{
    __shared__ float tanY[2049];
    __shared__ float tanD[2049];
    // (W_ih, b_ih+b_hh) pairs indexed [T][hi][r] -> per-wave reads broadcast
    __shared__ __align__(16) float2 wib[256];
    // prebuilt g-dot A-fragments (row 0 = wg), 2 frags x 64 lanes x 16B
    __shared__ __align__(16) bf16x8 wgF[2 * 64];
    // h double buffer: 2 x 16 rows(cells) x 144B (64 bf16 + pad)
    __shared__ __align__(16) char hbuf[2 * 16 * 144];

    const int tid  = threadIdx.x;
    const int wv   = tid >> 6;          // 0..7: 8-hdim slice
    const int lane = tid & 63;
    const int lo   = lane & 15;
    const int hi   = lane >> 4;

    // ---- build tanh table (one-time): tanh on [-8, 8], step 1/128 ----
    for (int idx = tid; idx < 2049; idx += 512) {
        const float xv = (float)idx * 0.0078125f - 8.0f;
        const float e0 = __builtin_amdgcn_exp2f(2.0f * LOG2E * xv);
        const float e1 = __builtin_amdgcn_exp2f(2.0f * LOG2E * (xv + 0.0078125f));
        const float t0 = 1.0f - 2.0f / (1.0f + e0);
        const float t1 = 1.0f - 2.0f / (1.0f + e1);
        tanY[idx] = t0;
        tanD[idx] = t1 - t0;
    }
    // ---- wib table: (W_ih[row], b_ih[row]+b_hh[row]), row = r*64 + 4T + h4 ----
    if (tid < 256) {
        const int T  = tid >> 4;
        const int h4 = (tid >> 2) & 3;
        const int r  = tid & 3;
        const int Wrow = r * 64 + 4 * T + h4;
        wib[tid] = make_float2(W_ih[Wrow], b_ih[Wrow] + b_hh[Wrow]);
    }
    // ---- wgF: g-dot A-fragments (built by wave 0, used by all) ----
    if (wv == 0) {
        #pragma unroll
        for (int kk = 0; kk < 2; ++kk) {
            bf16x8 v = {};
            if (lo == 0) {
                const float* src = wg + kk * 32 + hi * 8;
                #pragma unroll
                for (int e = 0; e < 8; ++e) v[e] = f2bf(src[e]);
            }
            wgF[kk * 64 + lane] = v;
        }
    }

    for (int o = tid; o < (2 * 16 * 144) / 4; o += 512)
        ((unsigned*)hbuf)[o] = 0u;      // h0 = 0 (both buffers)

    // ---- per-cell constants ----
    const int cell = blockIdx.x * 16 + lo;
    const int n    = cell & 63;
    float a_n = 0.f, c_n = 0.f;
    #pragma unroll
    for (int k = 0; k < 10; ++k) {
        a_n += w1[n * 10 + k] * w2[n * 10 + k];   // per-neuron affine collapse
        c_n += b1[n * 10 + k] * w2[n * 10 + k];
    }
    c_n += b2[n];
    const float bgv = bg[0];

    // ---- A-fragments (gate-interleaved tiles), K=64, VGPR-resident ----
    bf16x8 AWf[2][2];
    #pragma unroll
    for (int t2 = 0; t2 < 2; ++t2) {
        const int T    = 2 * wv + t2;
        const int Wrow = (lo & 3) * 64 + 4 * T + (lo >> 2);
        #pragma unroll
        for (int kk = 0; kk < 2; ++kk) {
            const float* src = W_hh + Wrow * 64 + kk * 32 + hi * 8;
            bf16x8 v;
            #pragma unroll
            for (int e = 0; e < 8; ++e) v[e] = f2bf(src[e]);
            AWf[t2][kk] = v;
        }
    }

    const f32x4 zero4 = {0.f, 0.f, 0.f, 0.f};
    float cst[2] = {0.f, 0.f};          // c state for the lane's 2 elems
    float sp0 = 0.f;                    // softplus at t=0 (held by wave 1)
    float gA  = 0.f;                    // g delay register
    const float* inP  = input + cell;
    float*       outP = out + cell;
    float raw_next = inP[0];

    __syncthreads();                    // tables + h0 visible

    for (int t = 0; t < TT; ++t) {
        const float raw = raw_next;
        raw_next = inP[((t + 1) & (TT - 1)) * MCELLS];
        const float x = raw * a_n + c_n;            // outLin[t,cell]

        // h B-frags: cell = lo, hdims hi*8.. / 32+hi*8..  (full h, K=64)
        const char* hrd = hbuf + (t & 1) * 2304 + lo * 144;
        const bf16x8 bf0 = *(const bf16x8*)(hrd + hi * 16);
        const bf16x8 bf1 = *(const bf16x8*)(hrd + 64 + hi * 16);

        // g-dot (wave-uniform conditional, 1-in-8 steps per wave):
        // wave w needs gA at its output step t_out (t_out&7==wv), set at
        // t_out-1 -> compute when ((t+1)&7)==wv; plus fresh at t=1 for out[0].
        if ((((t + 1) & 7) == wv) || (t == 1 && wv == 1)) {
            const bf16x8 g0 = wgF[lane];
            const bf16x8 g1 = wgF[64 + lane];
            f32x4 accg;
            accg = __builtin_amdgcn_mfma_f32_16x16x32_bf16(g0, bf0, zero4, 0, 0, 0);
            accg = __builtin_amdgcn_mfma_f32_16x16x32_bf16(g1, bf1, accg, 0, 0, 0);
            gA = accg[0];               // g_{t-1} (valid on lanes hi==0)
        }

        f32x4 acc[2];
        #pragma unroll
        for (int t2 = 0; t2 < 2; ++t2) {
            // f32 acc init: gate r of (cell, hdim 4T+hi) = x*W_ih + bias
            const int base = (2 * wv + t2) * 16 + hi * 4;   // float2 index
            const f32x4 p01 = *(const f32x4*)&wib[base];     // (w0,b0,w1,b1)
            const f32x4 p23 = *(const f32x4*)&wib[base + 2]; // (w2,b2,w3,b3)
            f32x4 ai;
            ai[0] = fmaf(x, p01[0], p01[1]);
            ai[1] = fmaf(x, p01[2], p01[3]);
            ai[2] = fmaf(x, p23[0], p23[1]);
            ai[3] = fmaf(x, p23[2], p23[3]);
            ai = __builtin_amdgcn_mfma_f32_16x16x32_bf16(AWf[t2][0], bf0, ai, 0, 0, 0);
            acc[t2] = __builtin_amdgcn_mfma_f32_16x16x32_bf16(AWf[t2][1], bf1, ai, 0, 0, 0);
        }

        // activations (validated math): elem t2 = (cell=lo, hdim=8wv+4t2+hi)
        // acc[t2][r] = gate r: 0=i, 1=f, 2=g, 3=o. Single fused rcp.
        char* hw = hbuf + ((t + 1) & 1) * 2304 + lo * 144;
        #pragma unroll
        for (int t2 = 0; t2 < 2; ++t2) {
            const float ip = acc[t2][0];
            const float fp = acc[t2][1];
            const float gp = acc[t2][2];
            const float op = acc[t2][3];

            const float Ei = __builtin_amdgcn_exp2f(-LOG2E * ip);
            const float Ef = __builtin_amdgcn_exp2f(-LOG2E * fp);
            const float Eo = __builtin_amdgcn_exp2f(-LOG2E * op);

            float tg;
            LUT_TANH(gp, tg);

            const float A1  = 1.f + Ei;
            const float A2  = 1.f + Ef;
            const float Od  = 1.f + Eo;
            const float A12 = A1 * A2;
            const float R   = __builtin_amdgcn_rcpf(A12 * Od);
            // cp = [c*A1 + tg*A2] / (A1*A2);  hv = tanh(cp) / Od
            const float cp  = (cst[t2] * A1 + tg * A2) * (Od * R);
            cst[t2] = cp;

            float tc;
            LUT_TANH(cp, tc);
            const float hv = tc * (A12 * R);

            // h-write: bf16 at hdim d = 8*wv + 4*t2 + hi
            *(short*)(hw + 2 * (8 * wv + 4 * t2 + hi)) = f2bf(hv);
        }

        // output: out[t] = g_prev[t]*softplus(x-1); g_prev = {g_0, 1, g_{t-2}..}
        // round-robin: wave (t&7) handles step t (t=0 handled by wave 1).
        if (((t == 0) ? (wv == 1) : ((t & 7) == wv)) && hi == 0) {
            const float spE = __builtin_amdgcn_exp2f(LOG2E * (x - 1.f));
            const float sp  = LN2 * __builtin_amdgcn_logf(1.f + spE);
            if (t == 0) {
                sp0 = sp;                               // wave 1 holds sp_0
            } else if (t == 1) {
                outP[MCELLS] = sp;                      // g_prev[1] = 1
                outP[0] = (gA + bgv) * sp0;             // g_0 * sp_0 (fresh gA)
            } else {
                outP[t * MCELLS] = (gA + bgv) * sp;     // g_{t-2} * sp_t
            }
        }
        __syncthreads();                // h(t+1) visible to all waves
    }
}

extern "C" void kernel_launch(void* const* d_in, const int* in_sizes, int n_in,
                              void* d_out, int out_size, void* d_ws, size_t ws_size,
                              hipStream_t stream) {
    const float* input = (const float*)d_in[0];
    const float* w1    = (const float*)d_in[1];
    const float* b1    = (const float*)d_in[2];
    const float* w2    = (const float*)d_in[3];
    const float* b2    = (const float*)d_in[4];
    const float* W_ih  = (const float*)d_in[5];
    const float* W_hh  = (const float*)d_in[6];
    const float* b_ih  = (const float*)d_in[7];
    const float* b_hh  = (const float*)d_in[8];
    const float* wg    = (const float*)d_in[9];
    const float* bg    = (const float*)d_in[10];

    lstm_net_kernel<<<dim3(1024), dim3(512), 0, stream>>>(
        input, w1, b1, w2, b2, W_ih, W_hh, b_ih, b_hh, wg, bg, (float*)d_out);
}

// Round 15
// 824.456 us; speedup vs baseline: 1.0005x; 1.0005x over previous
//
#include <hip/hip_runtime.h>
#include <hip/hip_bf16.h>

#define TT 512
#define MCELLS 16384            // B*N = 256*64
#define LOG2E 1.44269504088896340736f
#define LN2   0.69314718055994530942f

typedef __attribute__((ext_vector_type(8))) short bf16x8;
typedef __attribute__((ext_vector_type(4))) float f32x4;

__device__ __forceinline__ short f2bf(float f) {
    __hip_bfloat16 h = __float2bfloat16(f);
    return __builtin_bit_cast(short, h);
}

// Validated tanh LUT (R10): DIRECT array indexing only. (sigma-via-LUT failed
// 3x at ~3e-2 -- R8/R9/R11 anomaly, abandoned. sigma stays on exp2.)
// tanh table: domain [-8,8], step 1/128, 2048 intervals + guard.
#define LUT_TANH(xv, dst) {                                            \
    const float _c = __builtin_amdgcn_fmed3f((xv), -8.0f, 7.9921875f); \
    const float _u = fmaf(_c, 128.0f, 1024.0f);                        \
    const int   _i = (int)_u;                                          \
    const float _f = _u - (float)_i;                                   \
    (dst) = fmaf(_f, tanD[_i], tanY[_i]); }

// Persistent LSTM, 8 waves/SIMD, register diet v2 (R13 still spilled).
// grid = 1024 blocks x 512 threads (8 waves) = 4 blocks/CU = 32 waves/CU.
// Block owns 16 cells (cell = blockIdx*16 + (lane&15)). Wave w owns hdims
// [8w, 8w+8) via TWO gate-interleaved 16x16 MFMA tiles T = 2w, 2w+1:
//   tile T row rho = (gate = rho&3, hdim = 4T + (rho>>2))
// giving acc[t2][r] = gate r of (cell=lane&15, hdim=4T+hi): complete
// (i,f,g,o) quads, 2 elems/lane. Bias/x*W_ih via f32 init from LDS wib.
// Diet v2: g-dot MFMA is CONDITIONAL (wave w needs accg only at steps
// (t+1)&7==wv, 1-in-8) with its A-fragments reloaded from LDS (wgF) inside
// the branch -- AWg is no longer persistent (-8 regs) and accg's transient
// window no longer overlaps the acc/activation peak. Single fused rcp per
// elem (R = rcp(A1*A2*Od)): trans/elem 5 -> 4.
__global__ __launch_bounds__(512, 8)
void lstm_net_kernel(const float* __restrict__ input,
                     const float* __restrict__ w1,
                     const float* __restrict__ b1,
                     const float* __restrict__ w2,
                     const float* __restrict__ b2,
                     const float* __restrict__ W_ih,
                     const float* __restrict__ W_hh,
                     const float* __restrict__ b_ih,
                     const float* __restrict__ b_hh,
                     const float* __restrict__ wg,
                     const float* __restrict__ bg,
                     float* __restrict__ out)
{
    __shared__ float tanY[2049];
    __shared__ float tanD[2049];
    // (W_ih, b_ih+b_hh) pairs indexed [T][hi][r] -> per-wave reads broadcast
    __shared__ __align__(16) float2 wib[256];
    // prebuilt g-dot A-fragments (row 0 = wg), 2 frags x 64 lanes x 16B
    __shared__ __align__(16) bf16x8 wgF[2 * 64];
    // h double buffer: 2 x 16 rows(cells) x 144B (64 bf16 + pad)
    __shared__ __align__(16) char hbuf[2 * 16 * 144];

    const int tid  = threadIdx.x;
    const int wv   = tid >> 6;          // 0..7: 8-hdim slice
    const int lane = tid & 63;
    const int lo   = lane & 15;
    const int hi   = lane >> 4;

    // ---- build tanh table (one-time): tanh on [-8, 8], step 1/128 ----
    for (int idx = tid; idx < 2049; idx += 512) {
        const float xv = (float)idx * 0.0078125f - 8.0f;
        const float e0 = __builtin_amdgcn_exp2f(2.0f * LOG2E * xv);
        const float e1 = __builtin_amdgcn_exp2f(2.0f * LOG2E * (xv + 0.0078125f));
        const float t0 = 1.0f - 2.0f / (1.0f + e0);
        const float t1 = 1.0f - 2.0f / (1.0f + e1);
        tanY[idx] = t0;
        tanD[idx] = t1 - t0;
    }
    // ---- wib table: (W_ih[row], b_ih[row]+b_hh[row]), row = r*64 + 4T + h4 ----
    if (tid < 256) {
        const int T  = tid >> 4;
        const int h4 = (tid >> 2) & 3;
        const int r  = tid & 3;
        const int Wrow = r * 64 + 4 * T + h4;
        wib[tid] = make_float2(W_ih[Wrow], b_ih[Wrow] + b_hh[Wrow]);
    }
    // ---- wgF: g-dot A-fragments (built by wave 0, used by all) ----
    if (wv == 0) {
        #pragma unroll
        for (int kk = 0; kk < 2; ++kk) {
            bf16x8 v = {};
            if (lo == 0) {
                const float* src = wg + kk * 32 + hi * 8;
                #pragma unroll
                for (int e = 0; e < 8; ++e) v[e] = f2bf(src[e]);
            }
            wgF[kk * 64 + lane] = v;
        }
    }

    for (int o = tid; o < (2 * 16 * 144) / 4; o += 512)
        ((unsigned*)hbuf)[o] = 0u;      // h0 = 0 (both buffers)

    // ---- per-cell constants ----
    const int cell = blockIdx.x * 16 + lo;
    const int n    = cell & 63;
    float a_n = 0.f, c_n = 0.f;
    #pragma unroll
    for (int k = 0; k < 10; ++k) {
        a_n += w1[n * 10 + k] * w2[n * 10 + k];   // per-neuron affine collapse
        c_n += b1[n * 10 + k] * w2[n * 10 + k];
    }
    c_n += b2[n];
    const float bgv = bg[0];

    // ---- A-fragments (gate-interleaved tiles), K=64, VGPR-resident ----
    bf16x8 AWf[2][2];
    #pragma unroll
    for (int t2 = 0; t2 < 2; ++t2) {
        const int T    = 2 * wv + t2;
        const int Wrow = (lo & 3) * 64 + 4 * T + (lo >> 2);
        #pragma unroll
        for (int kk = 0; kk < 2; ++kk) {
            const float* src = W_hh + Wrow * 64 + kk * 32 + hi * 8;
            bf16x8 v;
            #pragma unroll
            for (int e = 0; e < 8; ++e) v[e] = f2bf(src[e]);
            AWf[t2][kk] = v;
        }
    }

    const f32x4 zero4 = {0.f, 0.f, 0.f, 0.f};
    float cst[2] = {0.f, 0.f};          // c state for the lane's 2 elems
    float sp0 = 0.f;                    // softplus at t=0 (held by wave 1)
    float gA  = 0.f;                    // g delay register
    const float* inP  = input + cell;
    float*       outP = out + cell;
    float raw_next = inP[0];

    __syncthreads();                    // tables + h0 visible

    for (int t = 0; t < TT; ++t) {
        const float raw = raw_next;
        raw_next = inP[((t + 1) & (TT - 1)) * MCELLS];
        const float x = raw * a_n + c_n;            // outLin[t,cell]

        // h B-frags: cell = lo, hdims hi*8.. / 32+hi*8..  (full h, K=64)
        const char* hrd = hbuf + (t & 1) * 2304 + lo * 144;
        const bf16x8 bf0 = *(const bf16x8*)(hrd + hi * 16);
        const bf16x8 bf1 = *(const bf16x8*)(hrd + 64 + hi * 16);

        // g-dot (wave-uniform conditional, 1-in-8 steps per wave):
        // wave w needs gA at its output step t_out (t_out&7==wv), set at
        // t_out-1 -> compute when ((t+1)&7)==wv; plus fresh at t=1 for out[0].
        if ((((t + 1) & 7) == wv) || (t == 1 && wv == 1)) {
            const bf16x8 g0 = wgF[lane];
            const bf16x8 g1 = wgF[64 + lane];
            f32x4 accg;
            accg = __builtin_amdgcn_mfma_f32_16x16x32_bf16(g0, bf0, zero4, 0, 0, 0);
            accg = __builtin_amdgcn_mfma_f32_16x16x32_bf16(g1, bf1, accg, 0, 0, 0);
            gA = accg[0];               // g_{t-1} (valid on lanes hi==0)
        }

        f32x4 acc[2];
        #pragma unroll
        for (int t2 = 0; t2 < 2; ++t2) {
            // f32 acc init: gate r of (cell, hdim 4T+hi) = x*W_ih + bias
            const int base = (2 * wv + t2) * 16 + hi * 4;   // float2 index
            const f32x4 p01 = *(const f32x4*)&wib[base];     // (w0,b0,w1,b1)
            const f32x4 p23 = *(const f32x4*)&wib[base + 2]; // (w2,b2,w3,b3)
            f32x4 ai;
            ai[0] = fmaf(x, p01[0], p01[1]);
            ai[1] = fmaf(x, p01[2], p01[3]);
            ai[2] = fmaf(x, p23[0], p23[1]);
            ai[3] = fmaf(x, p23[2], p23[3]);
            ai = __builtin_amdgcn_mfma_f32_16x16x32_bf16(AWf[t2][0], bf0, ai, 0, 0, 0);
            acc[t2] = __builtin_amdgcn_mfma_f32_16x16x32_bf16(AWf[t2][1], bf1, ai, 0, 0, 0);
        }

        // activations (validated math): elem t2 = (cell=lo, hdim=8wv+4t2+hi)
        // acc[t2][r] = gate r: 0=i, 1=f, 2=g, 3=o. Single fused rcp.
        char* hw = hbuf + ((t + 1) & 1) * 2304 + lo * 144;
        #pragma unroll
        for (int t2 = 0; t2 < 2; ++t2) {
            const float ip = acc[t2][0];
            const float fp = acc[t2][1];
            const float gp = acc[t2][2];
            const float op = acc[t2][3];

            const float Ei = __builtin_amdgcn_exp2f(-LOG2E * ip);
            const float Ef = __builtin_amdgcn_exp2f(-LOG2E * fp);
            const float Eo = __builtin_amdgcn_exp2f(-LOG2E * op);

            float tg;
            LUT_TANH(gp, tg);

            const float A1  = 1.f + Ei;
            const float A2  = 1.f + Ef;
            const float Od  = 1.f + Eo;
            const float A12 = A1 * A2;
            const float R   = __builtin_amdgcn_rcpf(A12 * Od);
            // cp = [c*A1 + tg*A2] / (A1*A2);  hv = tanh(cp) / Od
            const float cp  = (cst[t2] * A1 + tg * A2) * (Od * R);
            cst[t2] = cp;

            float tc;
            LUT_TANH(cp, tc);
            const float hv = tc * (A12 * R);

            // h-write: bf16 at hdim d = 8*wv + 4*t2 + hi
            *(short*)(hw + 2 * (8 * wv + 4 * t2 + hi)) = f2bf(hv);
        }

        // output: out[t] = g_prev[t]*softplus(x-1); g_prev = {g_0, 1, g_{t-2}..}
        // round-robin: wave (t&7) handles step t (t=0 handled by wave 1).
        if (((t == 0) ? (wv == 1) : ((t & 7) == wv)) && hi == 0) {
            const float spE = __builtin_amdgcn_exp2f(LOG2E * (x - 1.f));
            const float sp  = LN2 * __builtin_amdgcn_logf(1.f + spE);
            if (t == 0) {
                sp0 = sp;                               // wave 1 holds sp_0
            } else if (t == 1) {
                outP[MCELLS] = sp;                      // g_prev[1] = 1
                outP[0] = (gA + bgv) * sp0;             // g_0 * sp_0 (fresh gA)
            } else {
                outP[t * MCELLS] = (gA + bgv) * sp;     // g_{t-2} * sp_t
            }
        }
        __syncthreads();                // h(t+1) visible to all waves
    }
}

extern "C" void kernel_launch(void* const* d_in, const int* in_sizes, int n_in,
                              void* d_out, int out_size, void* d_ws, size_t ws_size,
                              hipStream_t stream) {
    const float* input = (const float*)d_in[0];
    const float* w1    = (const float*)d_in[1];
    const float* b1    = (const float*)d_in[2];
    const float* w2    = (const float*)d_in[3];
    const float* b2    = (const float*)d_in[4];
    const float* W_ih  = (const float*)d_in[5];
    const float* W_hh  = (const float*)d_in[6];
    const float* b_ih  = (const float*)d_in[7];
    const float* b_hh  = (const float*)d_in[8];
    const float* wg    = (const float*)d_in[9];
    const float* bg    = (const float*)d_in[10];

    lstm_net_kernel<<<dim3(1024), dim3(512), 0, stream>>>(
        input, w1, b1, w2, b2, W_ih, W_hh, b_ih, b_hh, wg, bg, (float*)d_out);
}

// Round 16
// 779.701 us; speedup vs baseline: 1.0579x; 1.0574x over previous
//
#include <hip/hip_runtime.h>
#include <hip/hip_bf16.h>

#define TT 512
#define MCELLS 16384            // B*N = 256*64
#define LOG2E 1.44269504088896340736f
#define LN2   0.69314718055994530942f

typedef __attribute__((ext_vector_type(8))) short bf16x8;
typedef __attribute__((ext_vector_type(4))) float f32x4;

__device__ __forceinline__ short f2bf(float f) {
    __hip_bfloat16 h = __float2bfloat16(f);
    return __builtin_bit_cast(short, h);
}
// two f32 -> packed bf16 dword (low16 = a, high16 = b), RNE in HW
__device__ __forceinline__ unsigned cvtpk(float a, float b) {
    unsigned r;
    asm("v_cvt_pk_bf16_f32 %0, %1, %2" : "=v"(r) : "v"(a), "v"(b));
    return r;
}

// Validated tanh LUT (R10): DIRECT array indexing only. (sigma-via-LUT failed
// 3x at ~3e-2 -- R8/R9/R11 anomaly, abandoned. sigma stays on exp2.)
// tanh table: domain [-8,8], step 1/128, 2048 intervals + guard.
#define LUT_TANH(xv, dst) {                                            \
    const float _c = __builtin_amdgcn_fmed3f((xv), -8.0f, 7.9921875f); \
    const float _u = fmaf(_c, 128.0f, 1024.0f);                        \
    const int   _i = (int)_u;                                          \
    const float _f = _u - (float)_i;                                   \
    (dst) = fmaf(_f, tanD[_i], tanY[_i]); }

// Persistent LSTM. grid = 1024 blocks x 256 threads (4 waves) = 4 blocks/CU
// over all 256 CUs, 4 waves/SIMD (128-reg budget -- no spill; the 8-wave
// variants R12-R14 all spilled at the 64-reg budget AND total issue rises
// with wave count due to duplicated per-wave overhead: abandoned on evidence).
// Block owns 16 cells (cell = blockIdx*16 + (lane&15)); wave w handles hdims
// [w*16, w*16+16) for all 4 gates (jm tile = gate*4 + w). Swapped MFMA
// D[gate-rows, cell], A = W_hh VGPR-resident, B = h^T from LDS.
// Validated fold-ins: f32 acc-init from LDS wib (replaces bias-MFMA; R13),
// conditional g-dot MFMA 1-in-4 steps (R14), single fused rcp/elem (R14),
// tanh via direct-indexed LDS LUT (R10).
__global__ __launch_bounds__(256, 4)
void lstm_net_kernel(const float* __restrict__ input,
                     const float* __restrict__ w1,
                     const float* __restrict__ b1,
                     const float* __restrict__ w2,
                     const float* __restrict__ b2,
                     const float* __restrict__ W_ih,
                     const float* __restrict__ W_hh,
                     const float* __restrict__ b_ih,
                     const float* __restrict__ b_hh,
                     const float* __restrict__ wg,
                     const float* __restrict__ bg,
                     float* __restrict__ out)
{
    __shared__ float tanY[2049];
    __shared__ float tanD[2049];
    // (W_ih[row], b_ih[row]+b_hh[row]) -- row = g*64 + wv*16 + 4*hi + r
    __shared__ __align__(16) float2 wib[256];
    // h double buffer: 2 x 16 rows(cells) x 144B (64 bf16 + pad)
    __shared__ __align__(16) char hbuf[2 * 16 * 144];

    const int tid  = threadIdx.x;
    const int wv   = tid >> 6;          // 0..3: 16-hdim slice
    const int lane = tid & 63;
    const int lo   = lane & 15;
    const int hi   = lane >> 4;

    // ---- build tanh table (one-time): tanh on [-8, 8], step 1/128 ----
    for (int idx = tid; idx < 2049; idx += 256) {
        const float xv = (float)idx * 0.0078125f - 8.0f;
        const float e0 = __builtin_amdgcn_exp2f(2.0f * LOG2E * xv);
        const float e1 = __builtin_amdgcn_exp2f(2.0f * LOG2E * (xv + 0.0078125f));
        const float t0 = 1.0f - 2.0f / (1.0f + e0);
        const float t1 = 1.0f - 2.0f / (1.0f + e1);
        tanY[idx] = t0;
        tanD[idx] = t1 - t0;
    }
    // ---- wib table ----
    if (tid < 256) {
        wib[tid] = make_float2(W_ih[tid], b_ih[tid] + b_hh[tid]);
    }

    for (int o = tid; o < (2 * 16 * 144) / 4; o += 256)
        ((unsigned*)hbuf)[o] = 0u;      // h0 = 0 (both buffers)

    // ---- per-cell constants ----
    const int cell = blockIdx.x * 16 + lo;
    const int n    = cell & 63;
    float a_n = 0.f, c_n = 0.f;
    #pragma unroll
    for (int k = 0; k < 10; ++k) {
        a_n += w1[n * 10 + k] * w2[n * 10 + k];   // per-neuron affine collapse
        c_n += b1[n * 10 + k] * w2[n * 10 + k];
    }
    c_n += b2[n];
    const float bgv = bg[0];

    // ---- A-fragments (K=64), VGPR-resident ----
    bf16x8 AWf[4][2];
    #pragma unroll
    for (int g = 0; g < 4; ++g) {
        const int row = (g * 4 + wv) * 16 + lo;
        #pragma unroll
        for (int kk = 0; kk < 2; ++kk) {
            const float* src = W_hh + row * 64 + kk * 32 + hi * 8;
            bf16x8 v;
            #pragma unroll
            for (int e = 0; e < 8; ++e) v[e] = f2bf(src[e]);
            AWf[g][kk] = v;
        }
    }
    // g-dot A-frags: row 0 = wg (lanes lo==0), rows 1..15 = 0
    bf16x8 AWg[2];
    #pragma unroll
    for (int kk = 0; kk < 2; ++kk) {
        bf16x8 v = {};
        if (lo == 0) {
            const float* src = wg + kk * 32 + hi * 8;
            #pragma unroll
            for (int e = 0; e < 8; ++e) v[e] = f2bf(src[e]);
        }
        AWg[kk] = v;
    }

    const f32x4 zero4 = {0.f, 0.f, 0.f, 0.f};
    f32x4 cst = zero4;                  // c state (4 elems/lane)
    float sp0 = 0.f;                    // softplus at t=0 (held by wave 1)
    float gA  = 0.f;                    // g delay register
    const float* inP  = input + cell;
    float*       outP = out + cell;
    float raw_next = inP[0];

    __syncthreads();                    // tables + h0 visible

    for (int t = 0; t < TT; ++t) {
        const float raw = raw_next;
        raw_next = inP[((t + 1) & (TT - 1)) * MCELLS];
        const float x = raw * a_n + c_n;            // outLin[t,cell]

        // h B-frags: cell = lo, hdims hi*8.. / 32+hi*8..
        const char* hrd = hbuf + (t & 1) * 2304 + lo * 144;
        const bf16x8 bf0 = *(const bf16x8*)(hrd + hi * 16);
        const bf16x8 bf1 = *(const bf16x8*)(hrd + 64 + hi * 16);

        // g-dot (wave-uniform conditional, 1-in-4 steps per wave):
        // wave w outputs at t&3==wv using gA = accg(t-1) -> compute when
        // ((t+1)&3)==wv; plus fresh at t=1 (wave 1) for out[0].
        if ((((t + 1) & 3) == wv) || (t == 1 && wv == 1)) {
            f32x4 accg;
            accg = __builtin_amdgcn_mfma_f32_16x16x32_bf16(AWg[0], bf0, zero4, 0, 0, 0);
            accg = __builtin_amdgcn_mfma_f32_16x16x32_bf16(AWg[1], bf1, accg, 0, 0, 0);
            gA = accg[0];               // g_{t-1} (valid on lanes hi==0)
        }

        f32x4 acc[4];
        #pragma unroll
        for (int g = 0; g < 4; ++g) {
            // f32 acc init: gate-row = g*64 + wv*16 + 4*hi + r
            const int base = g * 64 + wv * 16 + hi * 4;      // float2 index
            const f32x4 p01 = *(const f32x4*)&wib[base];      // (w0,b0,w1,b1)
            const f32x4 p23 = *(const f32x4*)&wib[base + 2];  // (w2,b2,w3,b3)
            f32x4 ai;
            ai[0] = fmaf(x, p01[0], p01[1]);
            ai[1] = fmaf(x, p01[2], p01[3]);
            ai[2] = fmaf(x, p23[0], p23[1]);
            ai[3] = fmaf(x, p23[2], p23[3]);
            ai = __builtin_amdgcn_mfma_f32_16x16x32_bf16(AWf[g][0], bf0, ai, 0, 0, 0);
            acc[g] = __builtin_amdgcn_mfma_f32_16x16x32_bf16(AWf[g][1], bf1, ai, 0, 0, 0);
        }

        // activations (validated math): lane owns (cell=lo, hdim=wv*16+4hi+r)
        float hv[4];
        #pragma unroll
        for (int r = 0; r < 4; ++r) {
            const float ip = acc[0][r];
            const float fp = acc[1][r];
            const float gp = acc[2][r];
            const float op = acc[3][r];

            const float Ei = __builtin_amdgcn_exp2f(-LOG2E * ip);
            const float Ef = __builtin_amdgcn_exp2f(-LOG2E * fp);
            const float Eo = __builtin_amdgcn_exp2f(-LOG2E * op);

            float tg;
            LUT_TANH(gp, tg);

            const float A1  = 1.f + Ei;
            const float A2  = 1.f + Ef;
            const float Od  = 1.f + Eo;
            const float A12 = A1 * A2;
            const float R   = __builtin_amdgcn_rcpf(A12 * Od);
            // cp = [c*A1 + tg*A2] / (A1*A2);  hv = tanh(cp) / Od
            const float cp  = (cst[r] * A1 + tg * A2) * (Od * R);
            cst[r] = cp;

            float tc;
            LUT_TANH(cp, tc);
            hv[r] = tc * (A12 * R);
        }
        // h-write: hdims wv*16 + hi*4 .. +4 at row lo
        uint2 pk;
        pk.x = cvtpk(hv[0], hv[1]);
        pk.y = cvtpk(hv[2], hv[3]);
        *(uint2*)(hbuf + ((t + 1) & 1) * 2304 + lo * 144 + wv * 32 + hi * 8) = pk;

        // output: out[t] = g_prev[t]*softplus(x-1); g_prev = {g_0, 1, g_{t-2}..}
        // round-robin: wave (t&3) handles step t (t=0 handled by wave 1).
        if (((t == 0) ? (wv == 1) : ((t & 3) == wv)) && hi == 0) {
            const float spE = __builtin_amdgcn_exp2f(LOG2E * (x - 1.f));
            const float sp  = LN2 * __builtin_amdgcn_logf(1.f + spE);
            if (t == 0) {
                sp0 = sp;                               // wave 1 holds sp_0
            } else if (t == 1) {
                outP[MCELLS] = sp;                      // g_prev[1] = 1
                outP[0] = (gA + bgv) * sp0;             // g_0 * sp_0 (fresh gA)
            } else {
                outP[t * MCELLS] = (gA + bgv) * sp;     // g_{t-2} * sp_t
            }
        }
        __syncthreads();                // h(t+1) visible to all waves
    }
}

extern "C" void kernel_launch(void* const* d_in, const int* in_sizes, int n_in,
                              void* d_out, int out_size, void* d_ws, size_t ws_size,
                              hipStream_t stream) {
    const float* input = (const float*)d_in[0];
    const float* w1    = (const float*)d_in[1];
    const float* b1    = (const float*)d_in[2];
    const float* w2    = (const float*)d_in[3];
    const float* b2    = (const float*)d_in[4];
    const float* W_ih  = (const float*)d_in[5];
    const float* W_hh  = (const float*)d_in[6];
    const float* b_ih  = (const float*)d_in[7];
    const float* b_hh  = (const float*)d_in[8];
    const float* wg    = (const float*)d_in[9];
    const float* bg    = (const float*)d_in[10];

    lstm_net_kernel<<<dim3(1024), dim3(256), 0, stream>>>(
        input, w1, b1, w2, b2, W_ih, W_hh, b_ih, b_hh, wg, bg, (float*)d_out);
}

// Round 17
// 706.979 us; speedup vs baseline: 1.1667x; 1.1029x over previous
//
#include <hip/hip_runtime.h>
#include <hip/hip_bf16.h>

#define TT 512
#define MCELLS 16384            // B*N = 256*64
#define LOG2E 1.44269504088896340736f
#define LN2   0.69314718055994530942f

typedef __attribute__((ext_vector_type(8))) short bf16x8;
typedef __attribute__((ext_vector_type(4))) float f32x4;
typedef __attribute__((ext_vector_type(4))) unsigned u32x4;

__device__ __forceinline__ short f2bf(float f) {
    __hip_bfloat16 h = __float2bfloat16(f);
    return __builtin_bit_cast(short, h);
}
// two f32 -> packed bf16 dword (low16 = a, high16 = b), RNE in HW
__device__ __forceinline__ unsigned cvtpk(float a, float b) {
    unsigned r;
    asm("v_cvt_pk_bf16_f32 %0, %1, %2" : "=v"(r) : "v"(a), "v"(b));
    return r;
}

// Persistent LSTM. grid = 1024 blocks x 256 threads (4 waves) = 4 blocks/CU
// over all 256 CUs, 4 waves/SIMD. (8-wave variants spilled at the 64-reg
// budget: abandoned. wib-LDS acc-init moved work onto the busiest pipe (LDS):
// reverted to the bias-ext MFMA -- matrix pipe is ~75% idle.)
// Block owns 16 cells (cell = blockIdx*16 + (lane&15)); wave w handles hdims
// [w*16, w*16+16) for all 4 gates (jm tile = gate*4 + w). Swapped MFMA
// D[gate-rows, cell], A = W_hh VGPR-resident, B = h^T from LDS. K=96: 3rd
// MFMA carries x*W_ih + bias (B-ext rows [x,1]).
// Validated pieces: tanh via direct-indexed LDS LUT (R10); conditional g-dot
// MFMA 1-in-4 steps (R14/R15); single fused rcp/elem (R15). New this round:
// (y,dy) fused into ONE float2 table -> 1 ds_read_b64 per lookup (halves the
// LUT gather count on the dominant LDS pipe).
__global__ __launch_bounds__(256, 4)
void lstm_net_kernel(const float* __restrict__ input,
                     const float* __restrict__ w1,
                     const float* __restrict__ b1,
                     const float* __restrict__ w2,
                     const float* __restrict__ b2,
                     const float* __restrict__ W_ih,
                     const float* __restrict__ W_hh,
                     const float* __restrict__ b_ih,
                     const float* __restrict__ b_hh,
                     const float* __restrict__ wg,
                     const float* __restrict__ bg,
                     float* __restrict__ out)
{
    __shared__ float2 tanYD[2049];      // (y, dy), domain [-8,8], step 1/128
    // h double buffer: 2 x 16 rows(cells) x 144B (64 bf16 + pad)
    __shared__ __align__(16) char hbuf[2 * 16 * 144];

// tanh LUT: direct indexing (validated R10); float2 fused read (this round).
#define LUT_TANH(xv, dst) {                                            \
    const float _c = __builtin_amdgcn_fmed3f((xv), -8.0f, 7.9921875f); \
    const float _u = fmaf(_c, 128.0f, 1024.0f);                        \
    const int   _i = (int)_u;                                          \
    const float _f = _u - (float)_i;                                   \
    const float2 _e = tanYD[_i];                                       \
    (dst) = fmaf(_f, _e.y, _e.x); }

    const int tid  = threadIdx.x;
    const int wv   = tid >> 6;          // 0..3: 16-hdim slice
    const int lane = tid & 63;
    const int lo   = lane & 15;
    const int hi   = lane >> 4;

    // ---- build tanh table (one-time): tanh on [-8, 8], step 1/128 ----
    for (int idx = tid; idx < 2049; idx += 256) {
        const float xv = (float)idx * 0.0078125f - 8.0f;
        const float e0 = __builtin_amdgcn_exp2f(2.0f * LOG2E * xv);
        const float e1 = __builtin_amdgcn_exp2f(2.0f * LOG2E * (xv + 0.0078125f));
        const float t0 = 1.0f - 2.0f / (1.0f + e0);
        const float t1 = 1.0f - 2.0f / (1.0f + e1);
        tanYD[idx] = make_float2(t0, t1 - t0);
    }

    for (int o = tid; o < (2 * 16 * 144) / 4; o += 256)
        ((unsigned*)hbuf)[o] = 0u;      // h0 = 0 (both buffers)

    // ---- per-cell constants ----
    const int cell = blockIdx.x * 16 + lo;
    const int n    = cell & 63;
    float a_n = 0.f, c_n = 0.f;
    #pragma unroll
    for (int k = 0; k < 10; ++k) {
        a_n += w1[n * 10 + k] * w2[n * 10 + k];   // per-neuron affine collapse
        c_n += b1[n * 10 + k] * w2[n * 10 + k];
    }
    c_n += b2[n];
    const float bgv = bg[0];

    // ---- A-fragments resident in VGPRs (K=96 incl bias-ext) ----
    bf16x8 AWf[4][3];
    #pragma unroll
    for (int g = 0; g < 4; ++g) {
        const int row = (g * 4 + wv) * 16 + lo;
        #pragma unroll
        for (int kk = 0; kk < 2; ++kk) {
            const float* src = W_hh + row * 64 + kk * 32 + hi * 8;
            bf16x8 v;
            #pragma unroll
            for (int e = 0; e < 8; ++e) v[e] = f2bf(src[e]);
            AWf[g][kk] = v;
        }
        bf16x8 vx = {};                 // K-ext: col64 = W_ih, col65 = bias
        if (hi == 0) {
            vx[0] = f2bf(W_ih[row]);
            vx[1] = f2bf(b_ih[row] + b_hh[row]);
        }
        AWf[g][2] = vx;
    }
    // g-dot A-frags: row 0 = wg (lanes lo==0), rows 1..15 = 0
    bf16x8 AWg[2];
    #pragma unroll
    for (int kk = 0; kk < 2; ++kk) {
        bf16x8 v = {};
        if (lo == 0) {
            const float* src = wg + kk * 32 + hi * 8;
            #pragma unroll
            for (int e = 0; e < 8; ++e) v[e] = f2bf(src[e]);
        }
        AWg[kk] = v;
    }

    const f32x4 zero4 = {0.f, 0.f, 0.f, 0.f};
    f32x4 cst = zero4;                  // c state (4 elems/lane)
    float sp0 = 0.f;                    // softplus at t=0 (held by wave 1)
    float gA  = 0.f;                    // g delay register
    const float* inP  = input + cell;
    float*       outP = out + cell;
    float raw_next = inP[0];

    __syncthreads();                    // table + h0 visible

    for (int t = 0; t < TT; ++t) {
        const float raw = raw_next;
        raw_next = inP[((t + 1) & (TT - 1)) * MCELLS];
        const float x = raw * a_n + c_n;            // outLin[t,cell]

        // B-ext frag: rows 64..95 of B = [x, 1, 0...] (per cell = lo)
        u32x4 bxi = {0u, 0u, 0u, 0u};
        bxi[0] = (hi == 0) ? cvtpk(x, 1.0f) : 0u;
        const bf16x8 bx = __builtin_bit_cast(bf16x8, bxi);

        // h B-frags: cell = lo, hdims hi*8.. / 32+hi*8..
        const char* hrd = hbuf + (t & 1) * 2304 + lo * 144;
        const bf16x8 bf0 = *(const bf16x8*)(hrd + hi * 16);
        const bf16x8 bf1 = *(const bf16x8*)(hrd + 64 + hi * 16);

        // g-dot (wave-uniform conditional, 1-in-4 steps per wave):
        // wave w outputs at t&3==wv using gA = accg(t-1) -> compute when
        // ((t+1)&3)==wv; plus fresh at t=1 (wave 1) for out[0].
        if ((((t + 1) & 3) == wv) || (t == 1 && wv == 1)) {
            f32x4 accg;
            accg = __builtin_amdgcn_mfma_f32_16x16x32_bf16(AWg[0], bf0, zero4, 0, 0, 0);
            accg = __builtin_amdgcn_mfma_f32_16x16x32_bf16(AWg[1], bf1, accg, 0, 0, 0);
            gA = accg[0];               // g_{t-1} (valid on lanes hi==0)
        }

        f32x4 acc[4];
        #pragma unroll
        for (int g = 0; g < 4; ++g) {
            acc[g] = __builtin_amdgcn_mfma_f32_16x16x32_bf16(AWf[g][2], bx,  zero4, 0, 0, 0);
            acc[g] = __builtin_amdgcn_mfma_f32_16x16x32_bf16(AWf[g][0], bf0, acc[g], 0, 0, 0);
            acc[g] = __builtin_amdgcn_mfma_f32_16x16x32_bf16(AWf[g][1], bf1, acc[g], 0, 0, 0);
        }

        // activations: lane owns (cell=lo, hdim = wv*16 + hi*4 + r)
        // sigma via exp2 (trans), tanh via float2 LDS LUT, single fused rcp.
        float hv[4];
        #pragma unroll
        for (int r = 0; r < 4; ++r) {
            const float ip = acc[0][r];
            const float fp = acc[1][r];
            const float gp = acc[2][r];
            const float op = acc[3][r];

            const float Ei = __builtin_amdgcn_exp2f(-LOG2E * ip);
            const float Ef = __builtin_amdgcn_exp2f(-LOG2E * fp);
            const float Eo = __builtin_amdgcn_exp2f(-LOG2E * op);

            float tg;
            LUT_TANH(gp, tg);

            const float A1  = 1.f + Ei;
            const float A2  = 1.f + Ef;
            const float Od  = 1.f + Eo;
            const float A12 = A1 * A2;
            const float R   = __builtin_amdgcn_rcpf(A12 * Od);
            // cp = [c*A1 + tg*A2] / (A1*A2);  hv = tanh(cp) / Od
            const float cp  = (cst[r] * A1 + tg * A2) * (Od * R);
            cst[r] = cp;

            float tc;
            LUT_TANH(cp, tc);
            hv[r] = tc * (A12 * R);
        }
        // h-write: hdims wv*16 + hi*4 .. +4 at row lo
        uint2 pk;
        pk.x = cvtpk(hv[0], hv[1]);
        pk.y = cvtpk(hv[2], hv[3]);
        *(uint2*)(hbuf + ((t + 1) & 1) * 2304 + lo * 144 + wv * 32 + hi * 8) = pk;

        // output: out[t] = g_prev[t]*softplus(x-1); g_prev = {g_0, 1, g_{t-2}..}
        // round-robin: wave (t&3) handles step t (t=0 handled by wave 1).
        if (((t == 0) ? (wv == 1) : ((t & 3) == wv)) && hi == 0) {
            const float spE = __builtin_amdgcn_exp2f(LOG2E * (x - 1.f));
            const float sp  = LN2 * __builtin_amdgcn_logf(1.f + spE);
            if (t == 0) {
                sp0 = sp;                               // wave 1 holds sp_0
            } else if (t == 1) {
                outP[MCELLS] = sp;                      // g_prev[1] = 1
                outP[0] = (gA + bgv) * sp0;             // g_0 * sp_0 (fresh gA)
            } else {
                outP[t * MCELLS] = (gA + bgv) * sp;     // g_{t-2} * sp_t
            }
        }
        __syncthreads();                // h(t+1) visible to all waves
    }
#undef LUT_TANH
}

extern "C" void kernel_launch(void* const* d_in, const int* in_sizes, int n_in,
                              void* d_out, int out_size, void* d_ws, size_t ws_size,
                              hipStream_t stream) {
    const float* input = (const float*)d_in[0];
    const float* w1    = (const float*)d_in[1];
    const float* b1    = (const float*)d_in[2];
    const float* w2    = (const float*)d_in[3];
    const float* b2    = (const float*)d_in[4];
    const float* W_ih  = (const float*)d_in[5];
    const float* W_hh  = (const float*)d_in[6];
    const float* b_ih  = (const float*)d_in[7];
    const float* b_hh  = (const float*)d_in[8];
    const float* wg    = (const float*)d_in[9];
    const float* bg    = (const float*)d_in[10];

    lstm_net_kernel<<<dim3(1024), dim3(256), 0, stream>>>(
        input, w1, b1, w2, b2, W_ih, W_hh, b_ih, b_hh, wg, bg, (float*)d_out);
}

// Round 18
// 698.777 us; speedup vs baseline: 1.1804x; 1.0117x over previous
//
#include <hip/hip_runtime.h>
#include <hip/hip_bf16.h>

#define TT 512
#define MCELLS 16384            // B*N = 256*64
#define LOG2E 1.44269504088896340736f
#define LN2   0.69314718055994530942f

typedef __attribute__((ext_vector_type(8))) short bf16x8;
typedef __attribute__((ext_vector_type(4))) float f32x4;
typedef __attribute__((ext_vector_type(4))) unsigned u32x4;

__device__ __forceinline__ short f2bf(float f) {
    __hip_bfloat16 h = __float2bfloat16(f);
    return __builtin_bit_cast(short, h);
}
// two f32 -> packed bf16 dword (low16 = a, high16 = b), RNE in HW
__device__ __forceinline__ unsigned cvtpk(float a, float b) {
    unsigned r;
    asm("v_cvt_pk_bf16_f32 %0, %1, %2" : "=v"(r) : "v"(a), "v"(b));
    return r;
}

// Persistent LSTM. grid = 1024 blocks x 256 threads (4 waves) = 4 blocks/CU
// over all 256 CUs, 4 waves/SIMD.
// Block owns 16 cells (cell = blockIdx*16 + (lane&15)); wave w handles hdims
// [w*16, w*16+16) for all 4 gates (jm tile = gate*4 + w). Swapped MFMA
// D[gate-rows, cell], A = W_hh VGPR-resident, B = h^T from LDS. K=96: 3rd
// MFMA carries x*W_ih + bias (B-ext rows [x,1]).
// Validated pieces: tanh via direct-indexed float2 LDS LUT (R10/R16);
// conditional g-dot MFMA 1-in-4 steps (R14/R15); single fused rcp (R15).
// NEW (R17): loop barrier = "s_waitcnt lgkmcnt(0); s_barrier" via inline asm
// -- skips the vmcnt(0) drain that __syncthreads() emits, so the per-step
// input prefetch (HBM latency) and the RR output store stay in flight across
// the barrier instead of stalling the whole block every step. Cross-barrier
// ordering requirement is LDS-only (h exchange); global accesses are
// lane-private and ordered by the compiler's own use-site waitcnts.
__global__ __launch_bounds__(256, 4)
void lstm_net_kernel(const float* __restrict__ input,
                     const float* __restrict__ w1,
                     const float* __restrict__ b1,
                     const float* __restrict__ w2,
                     const float* __restrict__ b2,
                     const float* __restrict__ W_ih,
                     const float* __restrict__ W_hh,
                     const float* __restrict__ b_ih,
                     const float* __restrict__ b_hh,
                     const float* __restrict__ wg,
                     const float* __restrict__ bg,
                     float* __restrict__ out)
{
    __shared__ float2 tanYD[2049];      // (y, dy), domain [-8,8], step 1/128
    // h double buffer: 2 x 16 rows(cells) x 144B (64 bf16 + pad)
    __shared__ __align__(16) char hbuf[2 * 16 * 144];

// tanh LUT: direct indexing (validated R10); float2 fused read (R16).
#define LUT_TANH(xv, dst) {                                            \
    const float _c = __builtin_amdgcn_fmed3f((xv), -8.0f, 7.9921875f); \
    const float _u = fmaf(_c, 128.0f, 1024.0f);                        \
    const int   _i = (int)_u;                                          \
    const float _f = _u - (float)_i;                                   \
    const float2 _e = tanYD[_i];                                       \
    (dst) = fmaf(_f, _e.y, _e.x); }

    const int tid  = threadIdx.x;
    const int wv   = tid >> 6;          // 0..3: 16-hdim slice
    const int lane = tid & 63;
    const int lo   = lane & 15;
    const int hi   = lane >> 4;

    // ---- build tanh table (one-time): tanh on [-8, 8], step 1/128 ----
    for (int idx = tid; idx < 2049; idx += 256) {
        const float xv = (float)idx * 0.0078125f - 8.0f;
        const float e0 = __builtin_amdgcn_exp2f(2.0f * LOG2E * xv);
        const float e1 = __builtin_amdgcn_exp2f(2.0f * LOG2E * (xv + 0.0078125f));
        const float t0 = 1.0f - 2.0f / (1.0f + e0);
        const float t1 = 1.0f - 2.0f / (1.0f + e1);
        tanYD[idx] = make_float2(t0, t1 - t0);
    }

    for (int o = tid; o < (2 * 16 * 144) / 4; o += 256)
        ((unsigned*)hbuf)[o] = 0u;      // h0 = 0 (both buffers)

    // ---- per-cell constants ----
    const int cell = blockIdx.x * 16 + lo;
    const int n    = cell & 63;
    float a_n = 0.f, c_n = 0.f;
    #pragma unroll
    for (int k = 0; k < 10; ++k) {
        a_n += w1[n * 10 + k] * w2[n * 10 + k];   // per-neuron affine collapse
        c_n += b1[n * 10 + k] * w2[n * 10 + k];
    }
    c_n += b2[n];
    const float bgv = bg[0];

    // ---- A-fragments resident in VGPRs (K=96 incl bias-ext) ----
    bf16x8 AWf[4][3];
    #pragma unroll
    for (int g = 0; g < 4; ++g) {
        const int row = (g * 4 + wv) * 16 + lo;
        #pragma unroll
        for (int kk = 0; kk < 2; ++kk) {
            const float* src = W_hh + row * 64 + kk * 32 + hi * 8;
            bf16x8 v;
            #pragma unroll
            for (int e = 0; e < 8; ++e) v[e] = f2bf(src[e]);
            AWf[g][kk] = v;
        }
        bf16x8 vx = {};                 // K-ext: col64 = W_ih, col65 = bias
        if (hi == 0) {
            vx[0] = f2bf(W_ih[row]);
            vx[1] = f2bf(b_ih[row] + b_hh[row]);
        }
        AWf[g][2] = vx;
    }
    // g-dot A-frags: row 0 = wg (lanes lo==0), rows 1..15 = 0
    bf16x8 AWg[2];
    #pragma unroll
    for (int kk = 0; kk < 2; ++kk) {
        bf16x8 v = {};
        if (lo == 0) {
            const float* src = wg + kk * 32 + hi * 8;
            #pragma unroll
            for (int e = 0; e < 8; ++e) v[e] = f2bf(src[e]);
        }
        AWg[kk] = v;
    }

    const f32x4 zero4 = {0.f, 0.f, 0.f, 0.f};
    f32x4 cst = zero4;                  // c state (4 elems/lane)
    float sp0 = 0.f;                    // softplus at t=0 (held by wave 1)
    float gA  = 0.f;                    // g delay register
    const float* inP  = input + cell;
    float*       outP = out + cell;
    float raw_next = inP[0];

    __syncthreads();                    // one-time full sync: tables + h0

    for (int t = 0; t < TT; ++t) {
        const float raw = raw_next;
        raw_next = inP[((t + 1) & (TT - 1)) * MCELLS];
        const float x = raw * a_n + c_n;            // outLin[t,cell]

        // B-ext frag: rows 64..95 of B = [x, 1, 0...] (per cell = lo)
        u32x4 bxi = {0u, 0u, 0u, 0u};
        bxi[0] = (hi == 0) ? cvtpk(x, 1.0f) : 0u;
        const bf16x8 bx = __builtin_bit_cast(bf16x8, bxi);

        // h B-frags: cell = lo, hdims hi*8.. / 32+hi*8..
        const char* hrd = hbuf + (t & 1) * 2304 + lo * 144;
        const bf16x8 bf0 = *(const bf16x8*)(hrd + hi * 16);
        const bf16x8 bf1 = *(const bf16x8*)(hrd + 64 + hi * 16);

        // g-dot (wave-uniform conditional, 1-in-4 steps per wave):
        // wave w outputs at t&3==wv using gA = accg(t-1) -> compute when
        // ((t+1)&3)==wv; plus fresh at t=1 (wave 1) for out[0].
        if ((((t + 1) & 3) == wv) || (t == 1 && wv == 1)) {
            f32x4 accg;
            accg = __builtin_amdgcn_mfma_f32_16x16x32_bf16(AWg[0], bf0, zero4, 0, 0, 0);
            accg = __builtin_amdgcn_mfma_f32_16x16x32_bf16(AWg[1], bf1, accg, 0, 0, 0);
            gA = accg[0];               // g_{t-1} (valid on lanes hi==0)
        }

        f32x4 acc[4];
        #pragma unroll
        for (int g = 0; g < 4; ++g) {
            acc[g] = __builtin_amdgcn_mfma_f32_16x16x32_bf16(AWf[g][2], bx,  zero4, 0, 0, 0);
            acc[g] = __builtin_amdgcn_mfma_f32_16x16x32_bf16(AWf[g][0], bf0, acc[g], 0, 0, 0);
            acc[g] = __builtin_amdgcn_mfma_f32_16x16x32_bf16(AWf[g][1], bf1, acc[g], 0, 0, 0);
        }

        // activations: lane owns (cell=lo, hdim = wv*16 + hi*4 + r)
        // sigma via exp2 (trans), tanh via float2 LDS LUT, single fused rcp.
        float hv[4];
        #pragma unroll
        for (int r = 0; r < 4; ++r) {
            const float ip = acc[0][r];
            const float fp = acc[1][r];
            const float gp = acc[2][r];
            const float op = acc[3][r];

            const float Ei = __builtin_amdgcn_exp2f(-LOG2E * ip);
            const float Ef = __builtin_amdgcn_exp2f(-LOG2E * fp);
            const float Eo = __builtin_amdgcn_exp2f(-LOG2E * op);

            float tg;
            LUT_TANH(gp, tg);

            const float A1  = 1.f + Ei;
            const float A2  = 1.f + Ef;
            const float Od  = 1.f + Eo;
            const float A12 = A1 * A2;
            const float R   = __builtin_amdgcn_rcpf(A12 * Od);
            // cp = [c*A1 + tg*A2] / (A1*A2);  hv = tanh(cp) / Od
            const float cp  = (cst[r] * A1 + tg * A2) * (Od * R);
            cst[r] = cp;

            float tc;
            LUT_TANH(cp, tc);
            hv[r] = tc * (A12 * R);
        }
        // h-write: hdims wv*16 + hi*4 .. +4 at row lo
        uint2 pk;
        pk.x = cvtpk(hv[0], hv[1]);
        pk.y = cvtpk(hv[2], hv[3]);
        *(uint2*)(hbuf + ((t + 1) & 1) * 2304 + lo * 144 + wv * 32 + hi * 8) = pk;

        // output: out[t] = g_prev[t]*softplus(x-1); g_prev = {g_0, 1, g_{t-2}..}
        // round-robin: wave (t&3) handles step t (t=0 handled by wave 1).
        if (((t == 0) ? (wv == 1) : ((t & 3) == wv)) && hi == 0) {
            const float spE = __builtin_amdgcn_exp2f(LOG2E * (x - 1.f));
            const float sp  = LN2 * __builtin_amdgcn_logf(1.f + spE);
            if (t == 0) {
                sp0 = sp;                               // wave 1 holds sp_0
            } else if (t == 1) {
                outP[MCELLS] = sp;                      // g_prev[1] = 1
                outP[0] = (gA + bgv) * sp0;             // g_0 * sp_0 (fresh gA)
            } else {
                outP[t * MCELLS] = (gA + bgv) * sp;     // g_{t-2} * sp_t
            }
        }

        // LDS-only barrier: drain lgkm (h-writes visible), do NOT drain vmcnt
        // -- input prefetch + output stores stay in flight across the barrier.
        // "memory" clobber pins compiler ordering of the surrounding ds ops.
        asm volatile("s_waitcnt lgkmcnt(0)\n\ts_barrier" ::: "memory");
    }
#undef LUT_TANH
}

extern "C" void kernel_launch(void* const* d_in, const int* in_sizes, int n_in,
                              void* d_out, int out_size, void* d_ws, size_t ws_size,
                              hipStream_t stream) {
    const float* input = (const float*)d_in[0];
    const float* w1    = (const float*)d_in[1];
    const float* b1    = (const float*)d_in[2];
    const float* w2    = (const float*)d_in[3];
    const float* b2    = (const float*)d_in[4];
    const float* W_ih  = (const float*)d_in[5];
    const float* W_hh  = (const float*)d_in[6];
    const float* b_ih  = (const float*)d_in[7];
    const float* b_hh  = (const float*)d_in[8];
    const float* wg    = (const float*)d_in[9];
    const float* bg    = (const float*)d_in[10];

    lstm_net_kernel<<<dim3(1024), dim3(256), 0, stream>>>(
        input, w1, b1, w2, b2, W_ih, W_hh, b_ih, b_hh, wg, bg, (float*)d_out);
}

// Round 19
// 622.064 us; speedup vs baseline: 1.3260x; 1.1233x over previous
//
#include <hip/hip_runtime.h>
#include <hip/hip_bf16.h>

#define TT 512
#define MCELLS 16384            // B*N = 256*64
#define LOG2E 1.44269504088896340736f
#define LN2   0.69314718055994530942f

typedef __attribute__((ext_vector_type(8))) short bf16x8;
typedef __attribute__((ext_vector_type(4))) float f32x4;
typedef __attribute__((ext_vector_type(4))) unsigned u32x4;

__device__ __forceinline__ short f2bf(float f) {
    __hip_bfloat16 h = __float2bfloat16(f);
    return __builtin_bit_cast(short, h);
}
// two f32 -> packed bf16 dword (low16 = a, high16 = b), RNE in HW
__device__ __forceinline__ unsigned cvtpk(float a, float b) {
    unsigned r;
    asm("v_cvt_pk_bf16_f32 %0, %1, %2" : "=v"(r) : "v"(a), "v"(b));
    return r;
}

// Persistent LSTM. grid = 1024 blocks x 256 threads (4 waves) = 4 blocks/CU
// over all 256 CUs, 4 waves/SIMD.
// Block owns 16 cells (cell = blockIdx*16 + (lane&15)); wave w handles hdims
// [w*16, w*16+16) for all 4 gates (jm tile = gate*4 + w). Swapped MFMA
// D[gate-rows, cell], A = W_hh VGPR-resident, B = h^T from LDS. K=96: 3rd
// MFMA carries x*W_ih + bias (B-ext rows [x,1]).
// Validated: conditional g-dot MFMA 1-in-4 steps (R14/R15); single fused rcp
// (R15); LDS-only loop barrier (R17). NEW (R18): tanh LUT is NEAREST-POINT
// f32, delta = 1/512 (8192 entries, 32 KB) -- one ds_read_b32 per lookup
// (halves LUT gather bytes, ~2 lanes/bank aliasing = free) and 2 fewer VALU
// per lookup. Error <= 1e-3, confined to the g/c additive/output paths which
// the bf16-h evidence proves contracting. sigma_f stays exp2-precise (the
// multiplicative-compounding path -- the sigma-LUT 3e-2 anomaly of R8/R9/R11).
__global__ __launch_bounds__(256, 4)
void lstm_net_kernel(const float* __restrict__ input,
                     const float* __restrict__ w1,
                     const float* __restrict__ b1,
                     const float* __restrict__ w2,
                     const float* __restrict__ b2,
                     const float* __restrict__ W_ih,
                     const float* __restrict__ W_hh,
                     const float* __restrict__ b_ih,
                     const float* __restrict__ b_hh,
                     const float* __restrict__ wg,
                     const float* __restrict__ bg,
                     float* __restrict__ out)
{
    __shared__ float tabT[8192];        // tanh((i-4096)/512), i = 0..8191
    // h double buffer: 2 x 16 rows(cells) x 144B (64 bf16 + pad)
    __shared__ __align__(16) char hbuf[2 * 16 * 144];

// tanh LUT: nearest-point, direct indexing. i = round(512*x) + 4096.
#define LUT_TANH(xv, dst) {                                              \
    const float _c = __builtin_amdgcn_fmed3f((xv), -8.0f, 7.998046875f); \
    const float _u = fmaf(_c, 512.0f, 4096.5f);                          \
    const int   _i = (int)_u;                                            \
    (dst) = tabT[_i]; }

    const int tid  = threadIdx.x;
    const int wv   = tid >> 6;          // 0..3: 16-hdim slice
    const int lane = tid & 63;
    const int lo   = lane & 15;
    const int hi   = lane >> 4;

    // ---- build tanh table (one-time): tanh on [-8, 8), step 1/512 ----
    for (int idx = tid; idx < 8192; idx += 256) {
        const float xv = (float)(idx - 4096) * 0.001953125f;
        const float e  = __builtin_amdgcn_exp2f(2.0f * LOG2E * xv);
        tabT[idx] = 1.0f - 2.0f / (1.0f + e);
    }

    for (int o = tid; o < (2 * 16 * 144) / 4; o += 256)
        ((unsigned*)hbuf)[o] = 0u;      // h0 = 0 (both buffers)

    // ---- per-cell constants ----
    const int cell = blockIdx.x * 16 + lo;
    const int n    = cell & 63;
    float a_n = 0.f, c_n = 0.f;
    #pragma unroll
    for (int k = 0; k < 10; ++k) {
        a_n += w1[n * 10 + k] * w2[n * 10 + k];   // per-neuron affine collapse
        c_n += b1[n * 10 + k] * w2[n * 10 + k];
    }
    c_n += b2[n];
    const float bgv = bg[0];

    // ---- A-fragments resident in VGPRs (K=96 incl bias-ext) ----
    bf16x8 AWf[4][3];
    #pragma unroll
    for (int g = 0; g < 4; ++g) {
        const int row = (g * 4 + wv) * 16 + lo;
        #pragma unroll
        for (int kk = 0; kk < 2; ++kk) {
            const float* src = W_hh + row * 64 + kk * 32 + hi * 8;
            bf16x8 v;
            #pragma unroll
            for (int e = 0; e < 8; ++e) v[e] = f2bf(src[e]);
            AWf[g][kk] = v;
        }
        bf16x8 vx = {};                 // K-ext: col64 = W_ih, col65 = bias
        if (hi == 0) {
            vx[0] = f2bf(W_ih[row]);
            vx[1] = f2bf(b_ih[row] + b_hh[row]);
        }
        AWf[g][2] = vx;
    }
    // g-dot A-frags: row 0 = wg (lanes lo==0), rows 1..15 = 0
    bf16x8 AWg[2];
    #pragma unroll
    for (int kk = 0; kk < 2; ++kk) {
        bf16x8 v = {};
        if (lo == 0) {
            const float* src = wg + kk * 32 + hi * 8;
            #pragma unroll
            for (int e = 0; e < 8; ++e) v[e] = f2bf(src[e]);
        }
        AWg[kk] = v;
    }

    const f32x4 zero4 = {0.f, 0.f, 0.f, 0.f};
    f32x4 cst = zero4;                  // c state (4 elems/lane)
    float sp0 = 0.f;                    // softplus at t=0 (held by wave 1)
    float gA  = 0.f;                    // g delay register
    const float* inP  = input + cell;
    float*       outP = out + cell;
    float raw_next = inP[0];

    __syncthreads();                    // one-time full sync: table + h0

    for (int t = 0; t < TT; ++t) {
        const float raw = raw_next;
        raw_next = inP[((t + 1) & (TT - 1)) * MCELLS];
        const float x = raw * a_n + c_n;            // outLin[t,cell]

        // B-ext frag: rows 64..95 of B = [x, 1, 0...] (per cell = lo)
        u32x4 bxi = {0u, 0u, 0u, 0u};
        bxi[0] = (hi == 0) ? cvtpk(x, 1.0f) : 0u;
        const bf16x8 bx = __builtin_bit_cast(bf16x8, bxi);

        // h B-frags: cell = lo, hdims hi*8.. / 32+hi*8..
        const char* hrd = hbuf + (t & 1) * 2304 + lo * 144;
        const bf16x8 bf0 = *(const bf16x8*)(hrd + hi * 16);
        const bf16x8 bf1 = *(const bf16x8*)(hrd + 64 + hi * 16);

        // g-dot (wave-uniform conditional, 1-in-4 steps per wave):
        // wave w outputs at t&3==wv using gA = accg(t-1) -> compute when
        // ((t+1)&3)==wv; plus fresh at t=1 (wave 1) for out[0].
        if ((((t + 1) & 3) == wv) || (t == 1 && wv == 1)) {
            f32x4 accg;
            accg = __builtin_amdgcn_mfma_f32_16x16x32_bf16(AWg[0], bf0, zero4, 0, 0, 0);
            accg = __builtin_amdgcn_mfma_f32_16x16x32_bf16(AWg[1], bf1, accg, 0, 0, 0);
            gA = accg[0];               // g_{t-1} (valid on lanes hi==0)
        }

        f32x4 acc[4];
        #pragma unroll
        for (int g = 0; g < 4; ++g) {
            acc[g] = __builtin_amdgcn_mfma_f32_16x16x32_bf16(AWf[g][2], bx,  zero4, 0, 0, 0);
            acc[g] = __builtin_amdgcn_mfma_f32_16x16x32_bf16(AWf[g][0], bf0, acc[g], 0, 0, 0);
            acc[g] = __builtin_amdgcn_mfma_f32_16x16x32_bf16(AWf[g][1], bf1, acc[g], 0, 0, 0);
        }

        // activations: lane owns (cell=lo, hdim = wv*16 + hi*4 + r)
        // sigma via exp2 (trans), tanh via nearest-point LDS LUT, fused rcp.
        float hv[4];
        #pragma unroll
        for (int r = 0; r < 4; ++r) {
            const float ip = acc[0][r];
            const float fp = acc[1][r];
            const float gp = acc[2][r];
            const float op = acc[3][r];

            const float Ei = __builtin_amdgcn_exp2f(-LOG2E * ip);
            const float Ef = __builtin_amdgcn_exp2f(-LOG2E * fp);
            const float Eo = __builtin_amdgcn_exp2f(-LOG2E * op);

            float tg;
            LUT_TANH(gp, tg);

            const float A1  = 1.f + Ei;
            const float A2  = 1.f + Ef;
            const float Od  = 1.f + Eo;
            const float A12 = A1 * A2;
            const float R   = __builtin_amdgcn_rcpf(A12 * Od);
            // cp = [c*A1 + tg*A2] / (A1*A2);  hv = tanh(cp) / Od
            const float cp  = (cst[r] * A1 + tg * A2) * (Od * R);
            cst[r] = cp;

            float tc;
            LUT_TANH(cp, tc);
            hv[r] = tc * (A12 * R);
        }
        // h-write: hdims wv*16 + hi*4 .. +4 at row lo
        uint2 pk;
        pk.x = cvtpk(hv[0], hv[1]);
        pk.y = cvtpk(hv[2], hv[3]);
        *(uint2*)(hbuf + ((t + 1) & 1) * 2304 + lo * 144 + wv * 32 + hi * 8) = pk;

        // output: out[t] = g_prev[t]*softplus(x-1); g_prev = {g_0, 1, g_{t-2}..}
        // round-robin: wave (t&3) handles step t (t=0 handled by wave 1).
        if (((t == 0) ? (wv == 1) : ((t & 3) == wv)) && hi == 0) {
            const float spE = __builtin_amdgcn_exp2f(LOG2E * (x - 1.f));
            const float sp  = LN2 * __builtin_amdgcn_logf(1.f + spE);
            if (t == 0) {
                sp0 = sp;                               // wave 1 holds sp_0
            } else if (t == 1) {
                outP[MCELLS] = sp;                      // g_prev[1] = 1
                outP[0] = (gA + bgv) * sp0;             // g_0 * sp_0 (fresh gA)
            } else {
                outP[t * MCELLS] = (gA + bgv) * sp;     // g_{t-2} * sp_t
            }
        }

        // LDS-only barrier (R17): drain lgkm, leave vmcnt in flight.
        asm volatile("s_waitcnt lgkmcnt(0)\n\ts_barrier" ::: "memory");
    }
#undef LUT_TANH
}

extern "C" void kernel_launch(void* const* d_in, const int* in_sizes, int n_in,
                              void* d_out, int out_size, void* d_ws, size_t ws_size,
                              hipStream_t stream) {
    const float* input = (const float*)d_in[0];
    const float* w1    = (const float*)d_in[1];
    const float* b1    = (const float*)d_in[2];
    const float* w2    = (const float*)d_in[3];
    const float* b2    = (const float*)d_in[4];
    const float* W_ih  = (const float*)d_in[5];
    const float* W_hh  = (const float*)d_in[6];
    const float* b_ih  = (const float*)d_in[7];
    const float* b_hh  = (const float*)d_in[8];
    const float* wg    = (const float*)d_in[9];
    const float* bg    = (const float*)d_in[10];

    lstm_net_kernel<<<dim3(1024), dim3(256), 0, stream>>>(
        input, w1, b1, w2, b2, W_ih, W_hh, b_ih, b_hh, wg, bg, (float*)d_out);
}

// Round 20
// 615.800 us; speedup vs baseline: 1.3394x; 1.0102x over previous
//
#include <hip/hip_runtime.h>
#include <hip/hip_bf16.h>

#define TT 512
#define MCELLS 16384            // B*N = 256*64
#define LOG2E 1.44269504088896340736f
#define LN2   0.69314718055994530942f

typedef __attribute__((ext_vector_type(8))) short bf16x8;
typedef __attribute__((ext_vector_type(4))) float f32x4;
typedef __attribute__((ext_vector_type(4))) unsigned u32x4;

__device__ __forceinline__ short f2bf(float f) {
    __hip_bfloat16 h = __float2bfloat16(f);
    return __builtin_bit_cast(short, h);
}
// two f32 -> packed bf16 dword (low16 = a, high16 = b), RNE in HW
__device__ __forceinline__ unsigned cvtpk(float a, float b) {
    unsigned r;
    asm("v_cvt_pk_bf16_f32 %0, %1, %2" : "=v"(r) : "v"(a), "v"(b));
    return r;
}

// Persistent LSTM. grid = 1024 blocks x 256 threads (4 waves) = 4 blocks/CU
// over all 256 CUs, 4 waves/SIMD.
// Block owns 16 cells (cell = blockIdx*16 + (lane&15)); wave w handles hdims
// [w*16, w*16+16) for all 4 gates (jm tile = gate*4 + w). Swapped MFMA
// D[gate-rows, cell], A = W_hh VGPR-resident, B = h^T from LDS. K=96: 3rd
// MFMA carries x*W_ih + bias (B-ext rows [x,1]).
// Validated: conditional g-dot MFMA 1-in-4 steps (R14/R15); LDS-only loop
// barrier (R17); nearest-point f32 tanh LUT delta=1/512 (R18).
// NEW (R19): sigma_i and sigma_o via the SAME tanh table
// (sigma(x) = 0.5 + 0.5*tanh(x/2), index = round(256x)+4096) -- removes 2 of
// 3 exp2 per elem (trans pipe was ~25-30% of SIMD time). sigma_f STAYS
// exp2+rcp precise: it multiplies c each step (compounding path) and is the
// suspected poison in the R8/R9/R11 sigma-LUT 3e-2 anomaly (those had ALL
// sigmas in LUT). This round is the isolating arm of that hypothesis.
__global__ __launch_bounds__(256, 4)
void lstm_net_kernel(const float* __restrict__ input,
                     const float* __restrict__ w1,
                     const float* __restrict__ b1,
                     const float* __restrict__ w2,
                     const float* __restrict__ b2,
                     const float* __restrict__ W_ih,
                     const float* __restrict__ W_hh,
                     const float* __restrict__ b_ih,
                     const float* __restrict__ b_hh,
                     const float* __restrict__ wg,
                     const float* __restrict__ bg,
                     float* __restrict__ out)
{
    __shared__ float tabT[8192];        // tanh((i-4096)/512), i = 0..8191
    // h double buffer: 2 x 16 rows(cells) x 144B (64 bf16 + pad)
    __shared__ __align__(16) char hbuf[2 * 16 * 144];

// tanh LUT: nearest-point, direct indexing. i = round(512*x) + 4096.
#define LUT_TANH(xv, dst) {                                              \
    const float _c = __builtin_amdgcn_fmed3f((xv), -8.0f, 7.998046875f); \
    const float _u = fmaf(_c, 512.0f, 4096.5f);                          \
    const int   _i = (int)_u;                                            \
    (dst) = tabT[_i]; }
// sigmoid via the SAME table: sigma(x) = 0.5 + 0.5*tanh(x/2);
// index = round(512*(x/2)) + 4096 = round(256*x) + 4096, domain [-16,16).
#define LUT_SIGT(xv, dst) {                                              \
    const float _c = __builtin_amdgcn_fmed3f((xv), -16.0f, 15.99609375f);\
    const float _u = fmaf(_c, 256.0f, 4096.5f);                          \
    const int   _i = (int)_u;                                            \
    (dst) = fmaf(0.5f, tabT[_i], 0.5f); }

    const int tid  = threadIdx.x;
    const int wv   = tid >> 6;          // 0..3: 16-hdim slice
    const int lane = tid & 63;
    const int lo   = lane & 15;
    const int hi   = lane >> 4;

    // ---- build tanh table (one-time): tanh on [-8, 8), step 1/512 ----
    for (int idx = tid; idx < 8192; idx += 256) {
        const float xv = (float)(idx - 4096) * 0.001953125f;
        const float e  = __builtin_amdgcn_exp2f(2.0f * LOG2E * xv);
        tabT[idx] = 1.0f - 2.0f / (1.0f + e);
    }

    for (int o = tid; o < (2 * 16 * 144) / 4; o += 256)
        ((unsigned*)hbuf)[o] = 0u;      // h0 = 0 (both buffers)

    // ---- per-cell constants ----
    const int cell = blockIdx.x * 16 + lo;
    const int n    = cell & 63;
    float a_n = 0.f, c_n = 0.f;
    #pragma unroll
    for (int k = 0; k < 10; ++k) {
        a_n += w1[n * 10 + k] * w2[n * 10 + k];   // per-neuron affine collapse
        c_n += b1[n * 10 + k] * w2[n * 10 + k];
    }
    c_n += b2[n];
    const float bgv = bg[0];

    // ---- A-fragments resident in VGPRs (K=96 incl bias-ext) ----
    bf16x8 AWf[4][3];
    #pragma unroll
    for (int g = 0; g < 4; ++g) {
        const int row = (g * 4 + wv) * 16 + lo;
        #pragma unroll
        for (int kk = 0; kk < 2; ++kk) {
            const float* src = W_hh + row * 64 + kk * 32 + hi * 8;
            bf16x8 v;
            #pragma unroll
            for (int e = 0; e < 8; ++e) v[e] = f2bf(src[e]);
            AWf[g][kk] = v;
        }
        bf16x8 vx = {};                 // K-ext: col64 = W_ih, col65 = bias
        if (hi == 0) {
            vx[0] = f2bf(W_ih[row]);
            vx[1] = f2bf(b_ih[row] + b_hh[row]);
        }
        AWf[g][2] = vx;
    }
    // g-dot A-frags: row 0 = wg (lanes lo==0), rows 1..15 = 0
    bf16x8 AWg[2];
    #pragma unroll
    for (int kk = 0; kk < 2; ++kk) {
        bf16x8 v = {};
        if (lo == 0) {
            const float* src = wg + kk * 32 + hi * 8;
            #pragma unroll
            for (int e = 0; e < 8; ++e) v[e] = f2bf(src[e]);
        }
        AWg[kk] = v;
    }

    const f32x4 zero4 = {0.f, 0.f, 0.f, 0.f};
    f32x4 cst = zero4;                  // c state (4 elems/lane)
    float sp0 = 0.f;                    // softplus at t=0 (held by wave 1)
    float gA  = 0.f;                    // g delay register
    const float* inP  = input + cell;
    float*       outP = out + cell;
    float raw_next = inP[0];

    __syncthreads();                    // one-time full sync: table + h0

    for (int t = 0; t < TT; ++t) {
        const float raw = raw_next;
        raw_next = inP[((t + 1) & (TT - 1)) * MCELLS];
        const float x = raw * a_n + c_n;            // outLin[t,cell]

        // B-ext frag: rows 64..95 of B = [x, 1, 0...] (per cell = lo)
        u32x4 bxi = {0u, 0u, 0u, 0u};
        bxi[0] = (hi == 0) ? cvtpk(x, 1.0f) : 0u;
        const bf16x8 bx = __builtin_bit_cast(bf16x8, bxi);

        // h B-frags: cell = lo, hdims hi*8.. / 32+hi*8..
        const char* hrd = hbuf + (t & 1) * 2304 + lo * 144;
        const bf16x8 bf0 = *(const bf16x8*)(hrd + hi * 16);
        const bf16x8 bf1 = *(const bf16x8*)(hrd + 64 + hi * 16);

        // g-dot (wave-uniform conditional, 1-in-4 steps per wave):
        // wave w outputs at t&3==wv using gA = accg(t-1) -> compute when
        // ((t+1)&3)==wv; plus fresh at t=1 (wave 1) for out[0].
        if ((((t + 1) & 3) == wv) || (t == 1 && wv == 1)) {
            f32x4 accg;
            accg = __builtin_amdgcn_mfma_f32_16x16x32_bf16(AWg[0], bf0, zero4, 0, 0, 0);
            accg = __builtin_amdgcn_mfma_f32_16x16x32_bf16(AWg[1], bf1, accg, 0, 0, 0);
            gA = accg[0];               // g_{t-1} (valid on lanes hi==0)
        }

        f32x4 acc[4];
        #pragma unroll
        for (int g = 0; g < 4; ++g) {
            acc[g] = __builtin_amdgcn_mfma_f32_16x16x32_bf16(AWf[g][2], bx,  zero4, 0, 0, 0);
            acc[g] = __builtin_amdgcn_mfma_f32_16x16x32_bf16(AWf[g][0], bf0, acc[g], 0, 0, 0);
            acc[g] = __builtin_amdgcn_mfma_f32_16x16x32_bf16(AWf[g][1], bf1, acc[g], 0, 0, 0);
        }

        // activations: lane owns (cell=lo, hdim = wv*16 + hi*4 + r)
        // sigma_f via exp2+rcp (precise, compounding path); sigma_i/sigma_o
        // and both tanh via nearest-point LDS LUT.
        float hv[4];
        #pragma unroll
        for (int r = 0; r < 4; ++r) {
            const float ip = acc[0][r];
            const float fp = acc[1][r];
            const float gp = acc[2][r];
            const float op = acc[3][r];

            const float Ef = __builtin_amdgcn_exp2f(-LOG2E * fp);

            float si, so, tg;
            LUT_SIGT(ip, si);
            LUT_SIGT(op, so);
            LUT_TANH(gp, tg);

            const float sf = __builtin_amdgcn_rcpf(1.f + Ef);
            const float cp = fmaf(sf, cst[r], si * tg);
            cst[r] = cp;

            float tc;
            LUT_TANH(cp, tc);
            hv[r] = so * tc;
        }
        // h-write: hdims wv*16 + hi*4 .. +4 at row lo
        uint2 pk;
        pk.x = cvtpk(hv[0], hv[1]);
        pk.y = cvtpk(hv[2], hv[3]);
        *(uint2*)(hbuf + ((t + 1) & 1) * 2304 + lo * 144 + wv * 32 + hi * 8) = pk;

        // output: out[t] = g_prev[t]*softplus(x-1); g_prev = {g_0, 1, g_{t-2}..}
        // round-robin: wave (t&3) handles step t (t=0 handled by wave 1).
        if (((t == 0) ? (wv == 1) : ((t & 3) == wv)) && hi == 0) {
            const float spE = __builtin_amdgcn_exp2f(LOG2E * (x - 1.f));
            const float sp  = LN2 * __builtin_amdgcn_logf(1.f + spE);
            if (t == 0) {
                sp0 = sp;                               // wave 1 holds sp_0
            } else if (t == 1) {
                outP[MCELLS] = sp;                      // g_prev[1] = 1
                outP[0] = (gA + bgv) * sp0;             // g_0 * sp_0 (fresh gA)
            } else {
                outP[t * MCELLS] = (gA + bgv) * sp;     // g_{t-2} * sp_t
            }
        }

        // LDS-only barrier (R17): drain lgkm, leave vmcnt in flight.
        asm volatile("s_waitcnt lgkmcnt(0)\n\ts_barrier" ::: "memory");
    }
#undef LUT_TANH
#undef LUT_SIGT
}

extern "C" void kernel_launch(void* const* d_in, const int* in_sizes, int n_in,
                              void* d_out, int out_size, void* d_ws, size_t ws_size,
                              hipStream_t stream) {
    const float* input = (const float*)d_in[0];
    const float* w1    = (const float*)d_in[1];
    const float* b1    = (const float*)d_in[2];
    const float* w2    = (const float*)d_in[3];
    const float* b2    = (const float*)d_in[4];
    const float* W_ih  = (const float*)d_in[5];
    const float* W_hh  = (const float*)d_in[6];
    const float* b_ih  = (const float*)d_in[7];
    const float* b_hh  = (const float*)d_in[8];
    const float* wg    = (const float*)d_in[9];
    const float* bg    = (const float*)d_in[10];

    lstm_net_kernel<<<dim3(1024), dim3(256), 0, stream>>>(
        input, w1, b1, w2, b2, W_ih, W_hh, b_ih, b_hh, wg, bg, (float*)d_out);
}

// Round 21
// 605.782 us; speedup vs baseline: 1.3616x; 1.0165x over previous
//
#include <hip/hip_runtime.h>
#include <hip/hip_bf16.h>

#define TT 512
#define MCELLS 16384            // B*N = 256*64
#define LOG2E 1.44269504088896340736f
#define LN2   0.69314718055994530942f

typedef __attribute__((ext_vector_type(8))) short bf16x8;
typedef __attribute__((ext_vector_type(4))) float f32x4;
typedef __attribute__((ext_vector_type(4))) unsigned u32x4;

__device__ __forceinline__ short f2bf(float f) {
    __hip_bfloat16 h = __float2bfloat16(f);
    return __builtin_bit_cast(short, h);
}
// two f32 -> packed bf16 dword (low16 = a, high16 = b), RNE in HW
__device__ __forceinline__ unsigned cvtpk(float a, float b) {
    unsigned r;
    asm("v_cvt_pk_bf16_f32 %0, %1, %2" : "=v"(r) : "v"(a), "v"(b));
    return r;
}

// Persistent LSTM. grid = 1024 blocks x 256 threads (4 waves) = 4 blocks/CU
// over all 256 CUs, 4 waves/SIMD.
// Block owns 16 cells (cell = blockIdx*16 + (lane&15)); wave w handles hdims
// [w*16, w*16+16) for all 4 gates (jm tile = gate*4 + w). Swapped MFMA
// D[gate-rows, cell], A = W_hh VGPR-resident, B = h^T from LDS. K=96: 3rd
// MFMA carries x*W_ih + bias (B-ext rows [x,1]).
// Validated: conditional g-dot MFMA 1-in-4 steps (R14/R15); LDS-only loop
// barrier (R17); nearest-point f32 tanh LUT delta=1/512 (R18); sigma_i/o via
// the same table (R19). sigma_f stays exp2+rcp: the three ~3e-2 LUT failures
// (R8/R9/R11) all had sigma_f in LUT -- it multiplies c every step
// (compounding path) -- while R19's sigma_i/o-LUT arm passed at 6.6e-4.
// NEW (R20): time loop unrolled x2 with explicit ping-pong bodies -- all LDS
// offsets become compile-time constants and the scheduler can slide step
// t+1's input/x/bx prep into step t's LUT-gather shadows. Math unchanged.
__global__ __launch_bounds__(256, 4)
void lstm_net_kernel(const float* __restrict__ input,
                     const float* __restrict__ w1,
                     const float* __restrict__ b1,
                     const float* __restrict__ w2,
                     const float* __restrict__ b2,
                     const float* __restrict__ W_ih,
                     const float* __restrict__ W_hh,
                     const float* __restrict__ b_ih,
                     const float* __restrict__ b_hh,
                     const float* __restrict__ wg,
                     const float* __restrict__ bg,
                     float* __restrict__ out)
{
    __shared__ float tabT[8192];        // tanh((i-4096)/512), i = 0..8191
    // h double buffer: 2 x 16 rows(cells) x 144B (64 bf16 + pad)
    __shared__ __align__(16) char hbuf[2 * 16 * 144];

// tanh LUT: nearest-point, direct indexing. i = round(512*x) + 4096.
#define LUT_TANH(xv, dst) {                                              \
    const float _c = __builtin_amdgcn_fmed3f((xv), -8.0f, 7.998046875f); \
    const float _u = fmaf(_c, 512.0f, 4096.5f);                          \
    const int   _i = (int)_u;                                            \
    (dst) = tabT[_i]; }
// sigmoid via the SAME table: sigma(x) = 0.5 + 0.5*tanh(x/2);
// index = round(256*x) + 4096, domain [-16,16).
#define LUT_SIGT(xv, dst) {                                              \
    const float _c = __builtin_amdgcn_fmed3f((xv), -16.0f, 15.99609375f);\
    const float _u = fmaf(_c, 256.0f, 4096.5f);                          \
    const int   _i = (int)_u;                                            \
    (dst) = fmaf(0.5f, tabT[_i], 0.5f); }

    const int tid  = threadIdx.x;
    const int wv   = tid >> 6;          // 0..3: 16-hdim slice
    const int lane = tid & 63;
    const int lo   = lane & 15;
    const int hi   = lane >> 4;

    // ---- build tanh table (one-time): tanh on [-8, 8), step 1/512 ----
    for (int idx = tid; idx < 8192; idx += 256) {
        const float xv = (float)(idx - 4096) * 0.001953125f;
        const float e  = __builtin_amdgcn_exp2f(2.0f * LOG2E * xv);
        tabT[idx] = 1.0f - 2.0f / (1.0f + e);
    }

    for (int o = tid; o < (2 * 16 * 144) / 4; o += 256)
        ((unsigned*)hbuf)[o] = 0u;      // h0 = 0 (both buffers)

    // ---- per-cell constants ----
    const int cell = blockIdx.x * 16 + lo;
    const int n    = cell & 63;
    float a_n = 0.f, c_n = 0.f;
    #pragma unroll
    for (int k = 0; k < 10; ++k) {
        a_n += w1[n * 10 + k] * w2[n * 10 + k];   // per-neuron affine collapse
        c_n += b1[n * 10 + k] * w2[n * 10 + k];
    }
    c_n += b2[n];
    const float bgv = bg[0];

    // ---- A-fragments resident in VGPRs (K=96 incl bias-ext) ----
    bf16x8 AWf[4][3];
    #pragma unroll
    for (int g = 0; g < 4; ++g) {
        const int row = (g * 4 + wv) * 16 + lo;
        #pragma unroll
        for (int kk = 0; kk < 2; ++kk) {
            const float* src = W_hh + row * 64 + kk * 32 + hi * 8;
            bf16x8 v;
            #pragma unroll
            for (int e = 0; e < 8; ++e) v[e] = f2bf(src[e]);
            AWf[g][kk] = v;
        }
        bf16x8 vx = {};                 // K-ext: col64 = W_ih, col65 = bias
        if (hi == 0) {
            vx[0] = f2bf(W_ih[row]);
            vx[1] = f2bf(b_ih[row] + b_hh[row]);
        }
        AWf[g][2] = vx;
    }
    // g-dot A-frags: row 0 = wg (lanes lo==0), rows 1..15 = 0
    bf16x8 AWg[2];
    #pragma unroll
    for (int kk = 0; kk < 2; ++kk) {
        bf16x8 v = {};
        if (lo == 0) {
            const float* src = wg + kk * 32 + hi * 8;
            #pragma unroll
            for (int e = 0; e < 8; ++e) v[e] = f2bf(src[e]);
        }
        AWg[kk] = v;
    }

    const f32x4 zero4 = {0.f, 0.f, 0.f, 0.f};
    f32x4 cst = zero4;                  // c state (4 elems/lane)
    float sp0 = 0.f;                    // softplus at t=0 (held by wave 1)
    float gA  = 0.f;                    // g delay register
    const float* inP  = input + cell;
    float*       outP = out + cell;
    float raw_next = inP[0];

    __syncthreads();                    // one-time full sync: table + h0

// One LSTM step. tt = step index; RDOFF/WROFF = compile-time buffer offsets.
#define STEP(tt, RDOFF, WROFF) {                                             \
        const float raw = raw_next;                                          \
        raw_next = inP[(((tt) + 1) & (TT - 1)) * MCELLS];                     \
        const float x = raw * a_n + c_n;                                      \
        u32x4 bxi = {0u, 0u, 0u, 0u};                                         \
        bxi[0] = (hi == 0) ? cvtpk(x, 1.0f) : 0u;                             \
        const bf16x8 bx = __builtin_bit_cast(bf16x8, bxi);                    \
        const char* hrd = hbuf + (RDOFF) + lo * 144;                          \
        const bf16x8 bf0 = *(const bf16x8*)(hrd + hi * 16);                   \
        const bf16x8 bf1 = *(const bf16x8*)(hrd + 64 + hi * 16);              \
        if (((((tt) + 1) & 3) == wv) || ((tt) == 1 && wv == 1)) {             \
            f32x4 accg;                                                       \
            accg = __builtin_amdgcn_mfma_f32_16x16x32_bf16(AWg[0], bf0, zero4, 0, 0, 0); \
            accg = __builtin_amdgcn_mfma_f32_16x16x32_bf16(AWg[1], bf1, accg, 0, 0, 0);  \
            gA = accg[0];                                                     \
        }                                                                     \
        f32x4 acc[4];                                                         \
        _Pragma("unroll")                                                     \
        for (int g = 0; g < 4; ++g) {                                         \
            acc[g] = __builtin_amdgcn_mfma_f32_16x16x32_bf16(AWf[g][2], bx,  zero4, 0, 0, 0);  \
            acc[g] = __builtin_amdgcn_mfma_f32_16x16x32_bf16(AWf[g][0], bf0, acc[g], 0, 0, 0); \
            acc[g] = __builtin_amdgcn_mfma_f32_16x16x32_bf16(AWf[g][1], bf1, acc[g], 0, 0, 0); \
        }                                                                     \
        float hv[4];                                                          \
        _Pragma("unroll")                                                     \
        for (int r = 0; r < 4; ++r) {                                         \
            const float ip = acc[0][r];                                       \
            const float fp = acc[1][r];                                       \
            const float gp = acc[2][r];                                       \
            const float op = acc[3][r];                                       \
            const float Ef = __builtin_amdgcn_exp2f(-LOG2E * fp);             \
            float si, so, tg;                                                 \
            LUT_SIGT(ip, si);                                                 \
            LUT_SIGT(op, so);                                                 \
            LUT_TANH(gp, tg);                                                 \
            const float sf = __builtin_amdgcn_rcpf(1.f + Ef);                 \
            const float cp = fmaf(sf, cst[r], si * tg);                       \
            cst[r] = cp;                                                      \
            float tc;                                                         \
            LUT_TANH(cp, tc);                                                 \
            hv[r] = so * tc;                                                  \
        }                                                                     \
        uint2 pk;                                                             \
        pk.x = cvtpk(hv[0], hv[1]);                                           \
        pk.y = cvtpk(hv[2], hv[3]);                                           \
        *(uint2*)(hbuf + (WROFF) + lo * 144 + wv * 32 + hi * 8) = pk;         \
        if ((((tt) == 0) ? (wv == 1) : (((tt) & 3) == wv)) && hi == 0) {      \
            const float spE = __builtin_amdgcn_exp2f(LOG2E * (x - 1.f));      \
            const float sp  = LN2 * __builtin_amdgcn_logf(1.f + spE);         \
            if ((tt) == 0) {                                                  \
                sp0 = sp;                                                     \
            } else if ((tt) == 1) {                                           \
                outP[MCELLS] = sp;                                            \
                outP[0] = (gA + bgv) * sp0;                                   \
            } else {                                                          \
                outP[(tt) * MCELLS] = (gA + bgv) * sp;                        \
            }                                                                 \
        }                                                                     \
        asm volatile("s_waitcnt lgkmcnt(0)\n\ts_barrier" ::: "memory");       \
    }

    for (int t = 0; t < TT; t += 2) {
        STEP(t,     0,    2304);        // read buf0, write buf1
        STEP(t + 1, 2304, 0);           // read buf1, write buf0
    }
#undef STEP
#undef LUT_TANH
#undef LUT_SIGT
}

extern "C" void kernel_launch(void* const* d_in, const int* in_sizes, int n_in,
                              void* d_out, int out_size, void* d_ws, size_t ws_size,
                              hipStream_t stream) {
    const float* input = (const float*)d_in[0];
    const float* w1    = (const float*)d_in[1];
    const float* b1    = (const float*)d_in[2];
    const float* w2    = (const float*)d_in[3];
    const float* b2    = (const float*)d_in[4];
    const float* W_ih  = (const float*)d_in[5];
    const float* W_hh  = (const float*)d_in[6];
    const float* b_ih  = (const float*)d_in[7];
    const float* b_hh  = (const float*)d_in[8];
    const float* wg    = (const float*)d_in[9];
    const float* bg    = (const float*)d_in[10];

    lstm_net_kernel<<<dim3(1024), dim3(256), 0, stream>>>(
        input, w1, b1, w2, b2, W_ih, W_hh, b_ih, b_hh, wg, bg, (float*)d_out);
}

// Round 22
// 603.195 us; speedup vs baseline: 1.3674x; 1.0043x over previous
//
#include <hip/hip_runtime.h>
#include <hip/hip_bf16.h>

#define TT 512
#define MCELLS 16384            // B*N = 256*64
#define LOG2E 1.44269504088896340736f
#define LN2   0.69314718055994530942f

typedef __attribute__((ext_vector_type(8))) short bf16x8;
typedef __attribute__((ext_vector_type(4))) float f32x4;
typedef __attribute__((ext_vector_type(4))) unsigned u32x4;

__device__ __forceinline__ short f2bf(float f) {
    __hip_bfloat16 h = __float2bfloat16(f);
    return __builtin_bit_cast(short, h);
}
// two f32 -> packed bf16 dword (low16 = a, high16 = b), RNE in HW
__device__ __forceinline__ unsigned cvtpk(float a, float b) {
    unsigned r;
    asm("v_cvt_pk_bf16_f32 %0, %1, %2" : "=v"(r) : "v"(a), "v"(b));
    return r;
}

// Persistent LSTM. grid = 1024 blocks x 256 threads (4 waves) = 4 blocks/CU
// over all 256 CUs, 4 waves/SIMD (one wave of each co-resident block/SIMD).
// Block owns 16 cells (cell = blockIdx*16 + (lane&15)); wave w handles hdims
// [w*16, w*16+16) for all 4 gates (jm tile = gate*4 + w). Swapped MFMA
// D[gate-rows, cell], A = W_hh VGPR-resident, B = h^T from LDS. K=96: 3rd
// MFMA carries x*W_ih + bias (B-ext rows [x,1]).
// Validated: conditional g-dot MFMA 1-in-4 steps (R14/R15); LDS-only loop
// barrier (R17); nearest-point f32 tanh LUT delta=1/512 (R18); sigma_i/o via
// the same table (R19); time loop unrolled x2 (R20). sigma_f stays exp2+rcp
// (the three ~3e-2 LUT failures R8/R9/R11 all had sigma_f in LUT; R19's
// sigma_i/o arm passed).
// NEW (R21): initial PHASE SKEW. All blocks run an identical barrier-paced
// stream launched together -> co-resident blocks are phase-locked, so their
// trans/gather/MFMA bursts collide on the shared units every step (the ~32%
// non-issue time). Skew co-resident blocks by quarter-step offsets
// (sel = ((bid>>8)+bid)&3, distinct for {c, c+256, c+512, c+768} under
// round-robin dispatch); barriers preserve the stagger thereafter.
__global__ __launch_bounds__(256, 4)
void lstm_net_kernel(const float* __restrict__ input,
                     const float* __restrict__ w1,
                     const float* __restrict__ b1,
                     const float* __restrict__ w2,
                     const float* __restrict__ b2,
                     const float* __restrict__ W_ih,
                     const float* __restrict__ W_hh,
                     const float* __restrict__ b_ih,
                     const float* __restrict__ b_hh,
                     const float* __restrict__ wg,
                     const float* __restrict__ bg,
                     float* __restrict__ out)
{
    __shared__ float tabT[8192];        // tanh((i-4096)/512), i = 0..8191
    // h double buffer: 2 x 16 rows(cells) x 144B (64 bf16 + pad)
    __shared__ __align__(16) char hbuf[2 * 16 * 144];

// tanh LUT: nearest-point, direct indexing. i = round(512*x) + 4096.
#define LUT_TANH(xv, dst) {                                              \
    const float _c = __builtin_amdgcn_fmed3f((xv), -8.0f, 7.998046875f); \
    const float _u = fmaf(_c, 512.0f, 4096.5f);                          \
    const int   _i = (int)_u;                                            \
    (dst) = tabT[_i]; }
// sigmoid via the SAME table: sigma(x) = 0.5 + 0.5*tanh(x/2);
// index = round(256*x) + 4096, domain [-16,16).
#define LUT_SIGT(xv, dst) {                                              \
    const float _c = __builtin_amdgcn_fmed3f((xv), -16.0f, 15.99609375f);\
    const float _u = fmaf(_c, 256.0f, 4096.5f);                          \
    const int   _i = (int)_u;                                            \
    (dst) = fmaf(0.5f, tabT[_i], 0.5f); }

    const int tid  = threadIdx.x;
    const int wv   = tid >> 6;          // 0..3: 16-hdim slice
    const int lane = tid & 63;
    const int lo   = lane & 15;
    const int hi   = lane >> 4;

    // ---- build tanh table (one-time): tanh on [-8, 8), step 1/512 ----
    for (int idx = tid; idx < 8192; idx += 256) {
        const float xv = (float)(idx - 4096) * 0.001953125f;
        const float e  = __builtin_amdgcn_exp2f(2.0f * LOG2E * xv);
        tabT[idx] = 1.0f - 2.0f / (1.0f + e);
    }

    for (int o = tid; o < (2 * 16 * 144) / 4; o += 256)
        ((unsigned*)hbuf)[o] = 0u;      // h0 = 0 (both buffers)

    // ---- per-cell constants ----
    const int cell = blockIdx.x * 16 + lo;
    const int n    = cell & 63;
    float a_n = 0.f, c_n = 0.f;
    #pragma unroll
    for (int k = 0; k < 10; ++k) {
        a_n += w1[n * 10 + k] * w2[n * 10 + k];   // per-neuron affine collapse
        c_n += b1[n * 10 + k] * w2[n * 10 + k];
    }
    c_n += b2[n];
    const float bgv = bg[0];

    // ---- A-fragments resident in VGPRs (K=96 incl bias-ext) ----
    bf16x8 AWf[4][3];
    #pragma unroll
    for (int g = 0; g < 4; ++g) {
        const int row = (g * 4 + wv) * 16 + lo;
        #pragma unroll
        for (int kk = 0; kk < 2; ++kk) {
            const float* src = W_hh + row * 64 + kk * 32 + hi * 8;
            bf16x8 v;
            #pragma unroll
            for (int e = 0; e < 8; ++e) v[e] = f2bf(src[e]);
            AWf[g][kk] = v;
        }
        bf16x8 vx = {};                 // K-ext: col64 = W_ih, col65 = bias
        if (hi == 0) {
            vx[0] = f2bf(W_ih[row]);
            vx[1] = f2bf(b_ih[row] + b_hh[row]);
        }
        AWf[g][2] = vx;
    }
    // g-dot A-frags: row 0 = wg (lanes lo==0), rows 1..15 = 0
    bf16x8 AWg[2];
    #pragma unroll
    for (int kk = 0; kk < 2; ++kk) {
        bf16x8 v = {};
        if (lo == 0) {
            const float* src = wg + kk * 32 + hi * 8;
            #pragma unroll
            for (int e = 0; e < 8; ++e) v[e] = f2bf(src[e]);
        }
        AWg[kk] = v;
    }

    const f32x4 zero4 = {0.f, 0.f, 0.f, 0.f};
    f32x4 cst = zero4;                  // c state (4 elems/lane)
    float sp0 = 0.f;                    // softplus at t=0 (held by wave 1)
    float gA  = 0.f;                    // g delay register
    const float* inP  = input + cell;
    float*       outP = out + cell;
    float raw_next = inP[0];

    __syncthreads();                    // one-time full sync: table + h0

    // ---- phase skew: decorrelate co-resident blocks (quarter-step each) ---
    {
        const unsigned sel = ((blockIdx.x >> 8) + blockIdx.x) & 3u;
        if (sel) {
            const long long tgt = (long long)(sel * 700u);
            const long long t0  = __builtin_amdgcn_s_memtime();
            while (__builtin_amdgcn_s_memtime() - t0 < tgt) { }
        }
    }

// One LSTM step. tt = step index; RDOFF/WROFF = compile-time buffer offsets.
#define STEP(tt, RDOFF, WROFF) {                                             \
        const float raw = raw_next;                                          \
        raw_next = inP[(((tt) + 1) & (TT - 1)) * MCELLS];                     \
        const float x = raw * a_n + c_n;                                      \
        u32x4 bxi = {0u, 0u, 0u, 0u};                                         \
        bxi[0] = (hi == 0) ? cvtpk(x, 1.0f) : 0u;                             \
        const bf16x8 bx = __builtin_bit_cast(bf16x8, bxi);                    \
        const char* hrd = hbuf + (RDOFF) + lo * 144;                          \
        const bf16x8 bf0 = *(const bf16x8*)(hrd + hi * 16);                   \
        const bf16x8 bf1 = *(const bf16x8*)(hrd + 64 + hi * 16);              \
        if (((((tt) + 1) & 3) == wv) || ((tt) == 1 && wv == 1)) {             \
            f32x4 accg;                                                       \
            accg = __builtin_amdgcn_mfma_f32_16x16x32_bf16(AWg[0], bf0, zero4, 0, 0, 0); \
            accg = __builtin_amdgcn_mfma_f32_16x16x32_bf16(AWg[1], bf1, accg, 0, 0, 0);  \
            gA = accg[0];                                                     \
        }                                                                     \
        f32x4 acc[4];                                                         \
        _Pragma("unroll")                                                     \
        for (int g = 0; g < 4; ++g) {                                         \
            acc[g] = __builtin_amdgcn_mfma_f32_16x16x32_bf16(AWf[g][2], bx,  zero4, 0, 0, 0);  \
            acc[g] = __builtin_amdgcn_mfma_f32_16x16x32_bf16(AWf[g][0], bf0, acc[g], 0, 0, 0); \
            acc[g] = __builtin_amdgcn_mfma_f32_16x16x32_bf16(AWf[g][1], bf1, acc[g], 0, 0, 0); \
        }                                                                     \
        float hv[4];                                                          \
        _Pragma("unroll")                                                     \
        for (int r = 0; r < 4; ++r) {                                         \
            const float ip = acc[0][r];                                       \
            const float fp = acc[1][r];                                       \
            const float gp = acc[2][r];                                       \
            const float op = acc[3][r];                                       \
            const float Ef = __builtin_amdgcn_exp2f(-LOG2E * fp);             \
            float si, so, tg;                                                 \
            LUT_SIGT(ip, si);                                                 \
            LUT_SIGT(op, so);                                                 \
            LUT_TANH(gp, tg);                                                 \
            const float sf = __builtin_amdgcn_rcpf(1.f + Ef);                 \
            const float cp = fmaf(sf, cst[r], si * tg);                       \
            cst[r] = cp;                                                      \
            float tc;                                                         \
            LUT_TANH(cp, tc);                                                 \
            hv[r] = so * tc;                                                  \
        }                                                                     \
        uint2 pk;                                                             \
        pk.x = cvtpk(hv[0], hv[1]);                                           \
        pk.y = cvtpk(hv[2], hv[3]);                                           \
        *(uint2*)(hbuf + (WROFF) + lo * 144 + wv * 32 + hi * 8) = pk;         \
        if ((((tt) == 0) ? (wv == 1) : (((tt) & 3) == wv)) && hi == 0) {      \
            const float spE = __builtin_amdgcn_exp2f(LOG2E * (x - 1.f));      \
            const float sp  = LN2 * __builtin_amdgcn_logf(1.f + spE);         \
            if ((tt) == 0) {                                                  \
                sp0 = sp;                                                     \
            } else if ((tt) == 1) {                                           \
                outP[MCELLS] = sp;                                            \
                outP[0] = (gA + bgv) * sp0;                                   \
            } else {                                                          \
                outP[(tt) * MCELLS] = (gA + bgv) * sp;                        \
            }                                                                 \
        }                                                                     \
        asm volatile("s_waitcnt lgkmcnt(0)\n\ts_barrier" ::: "memory");       \
    }

    for (int t = 0; t < TT; t += 2) {
        STEP(t,     0,    2304);        // read buf0, write buf1
        STEP(t + 1, 2304, 0);           // read buf1, write buf0
    }
#undef STEP
#undef LUT_TANH
#undef LUT_SIGT
}

extern "C" void kernel_launch(void* const* d_in, const int* in_sizes, int n_in,
                              void* d_out, int out_size, void* d_ws, size_t ws_size,
                              hipStream_t stream) {
    const float* input = (const float*)d_in[0];
    const float* w1    = (const float*)d_in[1];
    const float* b1    = (const float*)d_in[2];
    const float* w2    = (const float*)d_in[3];
    const float* b2    = (const float*)d_in[4];
    const float* W_ih  = (const float*)d_in[5];
    const float* W_hh  = (const float*)d_in[6];
    const float* b_ih  = (const float*)d_in[7];
    const float* b_hh  = (const float*)d_in[8];
    const float* wg    = (const float*)d_in[9];
    const float* bg    = (const float*)d_in[10];

    lstm_net_kernel<<<dim3(1024), dim3(256), 0, stream>>>(
        input, w1, b1, w2, b2, W_ih, W_hh, b_ih, b_hh, wg, bg, (float*)d_out);
}